// Round 5
// baseline (998.929 us; speedup 1.0000x reference)
//
#include <hip/hip_runtime.h>
#include <hip/hip_fp16.h>
#include <hip/hip_cooperative_groups.h>

namespace cg = cooperative_groups;

// GCN 2-layer forward, MI355X. R16: single cooperative kernel.
// R15 post-mortem: staged-gather pass floors at ~102us ~= u64-LDS-atomic
// pass (94us) — falsifier fired, sorted tier deleted. R12 structure is the
// per-edge-op floor (reorder 1xu32, count 1xu32, acc1/acc2 1xu64 each,
// ~3.5cyc/edge u64, ~1.8 u32). Remaining slack: 5 serial dispatches sum to
// ~356us kernel time vs 431us wall => ~75us inter-dispatch gap. Fix: fuse
// all phases into ONE hipLaunchCooperativeKernel dispatch, grid.sync()
// (+__threadfence for cross-XCD visibility) between phases, LDS union.
// Grid = NB(<=512) blocks x 512 thr, 60KB LDS -> 2 blocks/CU co-resident.
// Falsifier: total >= 430 => gap theory wrong; next lever = ds_pk_add_f16.

constexpr int W_SHIFT = 11;
constexpr int W = 2048;            // nodes per dst window
constexpr int MAXB = 512;          // max buckets/windows
constexpr int RB = 1024;           // tier-2 reorder block threads
constexpr int CHUNK = 8192;        // edges per reorder chunk
constexpr int CAP = 28;            // reorder slab capacity per bucket
constexpr int CT = 512;            // cooperative block threads
constexpr int AB = 512;            // tier-2 accumulate block threads

constexpr float SCALE1 = 65536.0f;
constexpr float INV1   = 1.0f / 65536.0f;
constexpr unsigned BIAS1 = 1u << 20;
constexpr float SCALE2 = 4096.0f;
constexpr float INV2   = 1.0f / 4096.0f;
constexpr unsigned BIAS2 = 1u << 22;

typedef unsigned uv4 __attribute__((ext_vector_type(4)));
typedef int      iv4 __attribute__((ext_vector_type(4)));

__device__ __forceinline__ unsigned long long pack2(float a, float b,
                                                    float scale, unsigned bias) {
    unsigned lo = (unsigned)(__float2int_rn(a * scale) + (int)bias);
    unsigned hi = (unsigned)(__float2int_rn(b * scale) + (int)bias);
    return (unsigned long long)lo | ((unsigned long long)hi << 32);
}

// ================== tier 1: single cooperative kernel ==================

__global__ __launch_bounds__(CT, 4) void k_fused(
    const int* __restrict__ src, const int* __restrict__ dst,
    const float2* __restrict__ x,
    const float* __restrict__ W1, const float* __restrict__ b1,
    const float* __restrict__ W2, const float* __restrict__ b2,
    unsigned* __restrict__ fill, unsigned* __restrict__ deg,
    __half2* __restrict__ xs, __half2* __restrict__ h2s,
    float2* __restrict__ out, unsigned* __restrict__ perm,
    int N, int E, unsigned C, int NB, int NCH)
{
    __shared__ union ShU {
        struct { unsigned slab[MAXB * CAP]; unsigned ptr[MAXB]; unsigned gbase[MAXB]; } r;
        unsigned cnt[2 * W];              // count phase (x2-replicated)
        unsigned long long acc[2 * W];    // acc phases (x2-replicated u64)
    } sh;
    cg::grid_group grid = cg::this_grid();
    const int tid = threadIdx.x;
    const int bid = blockIdx.x;
    const int b = bid;                    // window id for phases 2-4

    // ---------- phase 0: fill init (replaces k_zero_fill) ----------
    if (bid == 0 && tid < NB) fill[tid] = (unsigned)tid * C;
    grid.sync();

    // ---------- phase 1: slab reorder, grid-strided chunks ----------
    for (int cid = bid; cid < NCH; cid += gridDim.x) {
        if (tid < MAXB) sh.r.ptr[tid] = 0u;
        __syncthreads();
        long base0 = (long)cid * CHUNK;
        int total = (int)min((long)CHUNK, (long)E - base0);
        bool full = (total == CHUNK);
        if (full) {
            const iv4* dv4 = (const iv4*)(dst + base0);
            const iv4* sv4 = (const iv4*)(src + base0);
            #pragma unroll
            for (int k = 0; k < CHUNK / (4 * CT); k++) {   // 4 iters
                iv4 dq = dv4[k * CT + tid];
                iv4 sq = sv4[k * CT + tid];
                unsigned d, bb, val, lpos;
                d = (unsigned)dq.x; bb = d >> W_SHIFT;
                val = (unsigned)sq.x | ((d & (W - 1)) << 20);
                lpos = atomicAdd(&sh.r.ptr[bb], 1u);
                if (lpos < (unsigned)CAP) sh.r.slab[bb * CAP + lpos] = val;
                else perm[atomicAdd(&fill[bb], 1u)] = val;
                d = (unsigned)dq.y; bb = d >> W_SHIFT;
                val = (unsigned)sq.y | ((d & (W - 1)) << 20);
                lpos = atomicAdd(&sh.r.ptr[bb], 1u);
                if (lpos < (unsigned)CAP) sh.r.slab[bb * CAP + lpos] = val;
                else perm[atomicAdd(&fill[bb], 1u)] = val;
                d = (unsigned)dq.z; bb = d >> W_SHIFT;
                val = (unsigned)sq.z | ((d & (W - 1)) << 20);
                lpos = atomicAdd(&sh.r.ptr[bb], 1u);
                if (lpos < (unsigned)CAP) sh.r.slab[bb * CAP + lpos] = val;
                else perm[atomicAdd(&fill[bb], 1u)] = val;
                d = (unsigned)dq.w; bb = d >> W_SHIFT;
                val = (unsigned)sq.w | ((d & (W - 1)) << 20);
                lpos = atomicAdd(&sh.r.ptr[bb], 1u);
                if (lpos < (unsigned)CAP) sh.r.slab[bb * CAP + lpos] = val;
                else perm[atomicAdd(&fill[bb], 1u)] = val;
            }
        } else {
            for (int li = tid; li < total; li += CT) {
                unsigned d = (unsigned)dst[base0 + li];
                unsigned s = (unsigned)src[base0 + li];
                unsigned bb = d >> W_SHIFT;
                unsigned val = s | ((d & (W - 1)) << 20);
                unsigned lpos = atomicAdd(&sh.r.ptr[bb], 1u);
                if (lpos < (unsigned)CAP) sh.r.slab[bb * CAP + lpos] = val;
                else perm[atomicAdd(&fill[bb], 1u)] = val;
            }
        }
        __syncthreads();
        if (tid < MAXB) {
            unsigned cnt = min(sh.r.ptr[tid], (unsigned)CAP);
            sh.r.gbase[tid] = cnt ? atomicAdd(&fill[tid], cnt) : 0u;
            sh.r.ptr[tid] = cnt;
        }
        __syncthreads();
        for (int s2 = tid; s2 < MAXB * CAP; s2 += CT) {
            int b2 = s2 / CAP;
            int i2 = s2 - b2 * CAP;
            if (i2 < (int)sh.r.ptr[b2]) perm[sh.r.gbase[b2] + i2] = sh.r.slab[s2];
        }
        __syncthreads();   // protect ptr/slab before next chunk
    }
    __threadfence();
    grid.sync();

    // ---------- phase 2: degree count + deg + xs ----------
    {
        for (int i = tid; i < 2 * W; i += CT) sh.cnt[i] = 0u;
        __syncthreads();
        unsigned par = tid & 1u;
        unsigned s = (unsigned)b * C, e = fill[b];
        unsigned m = e - s, nv8 = m >> 3;
        const uv4* p4 = (const uv4*)(perm + s);
        for (unsigned j = tid; j < nv8; j += CT) {
            uv4 qa = __builtin_nontemporal_load(p4 + 2u * j);
            uv4 qb = __builtin_nontemporal_load(p4 + 2u * j + 1u);
            atomicAdd(&sh.cnt[((qa.x >> 20) << 1) | par], 1u);
            atomicAdd(&sh.cnt[((qa.y >> 20) << 1) | par], 1u);
            atomicAdd(&sh.cnt[((qa.z >> 20) << 1) | par], 1u);
            atomicAdd(&sh.cnt[((qa.w >> 20) << 1) | par], 1u);
            atomicAdd(&sh.cnt[((qb.x >> 20) << 1) | par], 1u);
            atomicAdd(&sh.cnt[((qb.y >> 20) << 1) | par], 1u);
            atomicAdd(&sh.cnt[((qb.z >> 20) << 1) | par], 1u);
            atomicAdd(&sh.cnt[((qb.w >> 20) << 1) | par], 1u);
        }
        unsigned t = s + (nv8 << 3) + (unsigned)tid;
        if (t < e) atomicAdd(&sh.cnt[((perm[t] >> 20) << 1) | par], 1u);
        __syncthreads();
        int d0 = b << W_SHIFT;
        for (int l = tid; l < W; l += CT) {
            int d = d0 + l;
            if (d < N) {
                unsigned cn = sh.cnt[2 * l] + sh.cnt[2 * l + 1];
                float dv = 1.0f / sqrtf((float)(cn + 1u));   // +1 self-loop
                deg[d] = cn;
                float2 xv = x[d];
                xs[d] = __floats2half2_rn(xv.x * dv, xv.y * dv);
            }
        }
    }
    __threadfence();
    grid.sync();

    // ---------- phase 3: layer-1 accumulate (u64 fixed-point) + MLP ----------
    {
        for (int i = tid; i < 2 * W; i += CT) sh.acc[i] = 0ull;
        __syncthreads();
        unsigned par = tid & 1u;
        unsigned s = (unsigned)b * C, e = fill[b];
        unsigned m = e - s, nv8 = m >> 3;
        const uv4* p4 = (const uv4*)(perm + s);
        for (unsigned j = tid; j < nv8; j += CT) {
            uv4 qa = __builtin_nontemporal_load(p4 + 2u * j);
            uv4 qb = __builtin_nontemporal_load(p4 + 2u * j + 1u);
            float2 v0 = __half22float2(xs[qa.x & 0xFFFFFu]);
            float2 v1 = __half22float2(xs[qa.y & 0xFFFFFu]);
            float2 v2 = __half22float2(xs[qa.z & 0xFFFFFu]);
            float2 v3 = __half22float2(xs[qa.w & 0xFFFFFu]);
            float2 v4 = __half22float2(xs[qb.x & 0xFFFFFu]);
            float2 v5 = __half22float2(xs[qb.y & 0xFFFFFu]);
            float2 v6 = __half22float2(xs[qb.z & 0xFFFFFu]);
            float2 v7 = __half22float2(xs[qb.w & 0xFFFFFu]);
            atomicAdd(&sh.acc[((qa.x >> 20) << 1) | par], pack2(v0.x, v0.y, SCALE1, BIAS1));
            atomicAdd(&sh.acc[((qa.y >> 20) << 1) | par], pack2(v1.x, v1.y, SCALE1, BIAS1));
            atomicAdd(&sh.acc[((qa.z >> 20) << 1) | par], pack2(v2.x, v2.y, SCALE1, BIAS1));
            atomicAdd(&sh.acc[((qa.w >> 20) << 1) | par], pack2(v3.x, v3.y, SCALE1, BIAS1));
            atomicAdd(&sh.acc[((qb.x >> 20) << 1) | par], pack2(v4.x, v4.y, SCALE1, BIAS1));
            atomicAdd(&sh.acc[((qb.y >> 20) << 1) | par], pack2(v5.x, v5.y, SCALE1, BIAS1));
            atomicAdd(&sh.acc[((qb.z >> 20) << 1) | par], pack2(v6.x, v6.y, SCALE1, BIAS1));
            atomicAdd(&sh.acc[((qb.w >> 20) << 1) | par], pack2(v7.x, v7.y, SCALE1, BIAS1));
        }
        unsigned t = s + (nv8 << 3) + (unsigned)tid;
        if (t < e) {
            unsigned p = perm[t];
            float2 v = __half22float2(xs[p & 0xFFFFFu]);
            atomicAdd(&sh.acc[((p >> 20) << 1) | par], pack2(v.x, v.y, SCALE1, BIAS1));
        }
        __syncthreads();
        int d0 = b << W_SHIFT;
        float w10 = W1[0], w11 = W1[1], w12 = W1[2], w13 = W1[3];
        float w14 = W1[4], w15 = W1[5], w16 = W1[6], w17 = W1[7];
        float bb0 = b1[0], bb1 = b1[1], bb2 = b1[2], bb3 = b1[3];
        float u0 = W2[0], u1 = W2[1], u2 = W2[2], u3 = W2[3];
        float u4 = W2[4], u5 = W2[5], u6 = W2[6], u7 = W2[7];
        for (int l = tid; l < W; l += CT) {
            int d = d0 + l;
            if (d < N) {
                unsigned cn = deg[d];
                float dv = 1.0f / sqrtf((float)(cn + 1u));
                unsigned long long a64 = sh.acc[2 * l] + sh.acc[2 * l + 1];
                unsigned lo = (unsigned)a64, hi = (unsigned)(a64 >> 32);
                float2 self = __half22float2(xs[d]);
                float Sx = (float)(int)(lo - cn * BIAS1) * INV1 + self.x;
                float Sy = (float)(int)(hi - cn * BIAS1) * INV1 + self.y;
                float a0 = fmaxf(fmaf(Sy, w14, Sx * w10) * dv + bb0, 0.0f);
                float a1 = fmaxf(fmaf(Sy, w15, Sx * w11) * dv + bb1, 0.0f);
                float a2 = fmaxf(fmaf(Sy, w16, Sx * w12) * dv + bb2, 0.0f);
                float a3 = fmaxf(fmaf(Sy, w17, Sx * w13) * dv + bb3, 0.0f);
                float hx = (a0 * u0 + a1 * u2 + a2 * u4 + a3 * u6) * dv;
                float hy = (a0 * u1 + a1 * u3 + a2 * u5 + a3 * u7) * dv;
                h2s[d] = __floats2half2_rn(hx, hy);
            }
        }
    }
    __threadfence();
    grid.sync();

    // ---------- phase 4: layer-2 accumulate (u64 fixed-point) + bias ----------
    {
        for (int i = tid; i < 2 * W; i += CT) sh.acc[i] = 0ull;
        __syncthreads();
        unsigned par = tid & 1u;
        unsigned s = (unsigned)b * C, e = fill[b];
        unsigned m = e - s, nv8 = m >> 3;
        const uv4* p4 = (const uv4*)(perm + s);
        for (unsigned j = tid; j < nv8; j += CT) {
            uv4 qa = __builtin_nontemporal_load(p4 + 2u * j);
            uv4 qb = __builtin_nontemporal_load(p4 + 2u * j + 1u);
            float2 v0 = __half22float2(h2s[qa.x & 0xFFFFFu]);
            float2 v1 = __half22float2(h2s[qa.y & 0xFFFFFu]);
            float2 v2 = __half22float2(h2s[qa.z & 0xFFFFFu]);
            float2 v3 = __half22float2(h2s[qa.w & 0xFFFFFu]);
            float2 v4 = __half22float2(h2s[qb.x & 0xFFFFFu]);
            float2 v5 = __half22float2(h2s[qb.y & 0xFFFFFu]);
            float2 v6 = __half22float2(h2s[qb.z & 0xFFFFFu]);
            float2 v7 = __half22float2(h2s[qb.w & 0xFFFFFu]);
            atomicAdd(&sh.acc[((qa.x >> 20) << 1) | par], pack2(v0.x, v0.y, SCALE2, BIAS2));
            atomicAdd(&sh.acc[((qa.y >> 20) << 1) | par], pack2(v1.x, v1.y, SCALE2, BIAS2));
            atomicAdd(&sh.acc[((qa.z >> 20) << 1) | par], pack2(v2.x, v2.y, SCALE2, BIAS2));
            atomicAdd(&sh.acc[((qa.w >> 20) << 1) | par], pack2(v3.x, v3.y, SCALE2, BIAS2));
            atomicAdd(&sh.acc[((qb.x >> 20) << 1) | par], pack2(v4.x, v4.y, SCALE2, BIAS2));
            atomicAdd(&sh.acc[((qb.y >> 20) << 1) | par], pack2(v5.x, v5.y, SCALE2, BIAS2));
            atomicAdd(&sh.acc[((qb.z >> 20) << 1) | par], pack2(v6.x, v6.y, SCALE2, BIAS2));
            atomicAdd(&sh.acc[((qb.w >> 20) << 1) | par], pack2(v7.x, v7.y, SCALE2, BIAS2));
        }
        unsigned t = s + (nv8 << 3) + (unsigned)tid;
        if (t < e) {
            unsigned p = perm[t];
            float2 v = __half22float2(h2s[p & 0xFFFFFu]);
            atomicAdd(&sh.acc[((p >> 20) << 1) | par], pack2(v.x, v.y, SCALE2, BIAS2));
        }
        __syncthreads();
        int d0 = b << W_SHIFT;
        float bb0 = b2[0], bb1 = b2[1];
        for (int l = tid; l < W; l += CT) {
            int d = d0 + l;
            if (d < N) {
                unsigned cn = deg[d];
                float dv = 1.0f / sqrtf((float)(cn + 1u));
                unsigned long long a64 = sh.acc[2 * l] + sh.acc[2 * l + 1];
                unsigned lo = (unsigned)a64, hi = (unsigned)(a64 >> 32);
                float2 v = __half22float2(h2s[d]);
                float Sx = (float)(int)(lo - cn * BIAS2) * INV2 + v.x;
                float Sy = (float)(int)(hi - cn * BIAS2) * INV2 + v.y;
                out[d] = make_float2(Sx * dv + bb0, Sy * dv + bb1);
            }
        }
    }
}

// ================== tier 2: R12 multi-kernel (proven 431us) ==================

__global__ __launch_bounds__(256) void k_zero_fill(unsigned* __restrict__ fill,
                                                   int nb, unsigned C) {
    int i = blockIdx.x * 256 + threadIdx.x;
    if (i < nb) fill[i] = (unsigned)i * C;
}

__global__ __launch_bounds__(RB) void k_reorder(const int* __restrict__ src,
                                                const int* __restrict__ dst,
                                                unsigned* __restrict__ fill,
                                                unsigned* __restrict__ perm, int E) {
    __shared__ unsigned slab[MAXB * CAP];
    __shared__ unsigned ptr[MAXB];
    __shared__ unsigned gbase[MAXB];
    int tid = threadIdx.x;
    if (tid < MAXB) ptr[tid] = 0u;
    __syncthreads();
    long base0 = (long)blockIdx.x * CHUNK;
    int total = (int)min((long)CHUNK, (long)E - base0);
    bool full = (total == CHUNK);
    if (full) {
        const iv4* dv4 = (const iv4*)(dst + base0);
        const iv4* sv4 = (const iv4*)(src + base0);
        #pragma unroll
        for (int k = 0; k < 2; k++) {
            iv4 dq = dv4[k * RB + tid];
            iv4 sq = sv4[k * RB + tid];
            unsigned d, bb, val, lpos;
            d = (unsigned)dq.x; bb = d >> W_SHIFT;
            val = (unsigned)sq.x | ((d & (W - 1)) << 20);
            lpos = atomicAdd(&ptr[bb], 1u);
            if (lpos < (unsigned)CAP) slab[bb * CAP + lpos] = val;
            else perm[atomicAdd(&fill[bb], 1u)] = val;
            d = (unsigned)dq.y; bb = d >> W_SHIFT;
            val = (unsigned)sq.y | ((d & (W - 1)) << 20);
            lpos = atomicAdd(&ptr[bb], 1u);
            if (lpos < (unsigned)CAP) slab[bb * CAP + lpos] = val;
            else perm[atomicAdd(&fill[bb], 1u)] = val;
            d = (unsigned)dq.z; bb = d >> W_SHIFT;
            val = (unsigned)sq.z | ((d & (W - 1)) << 20);
            lpos = atomicAdd(&ptr[bb], 1u);
            if (lpos < (unsigned)CAP) slab[bb * CAP + lpos] = val;
            else perm[atomicAdd(&fill[bb], 1u)] = val;
            d = (unsigned)dq.w; bb = d >> W_SHIFT;
            val = (unsigned)sq.w | ((d & (W - 1)) << 20);
            lpos = atomicAdd(&ptr[bb], 1u);
            if (lpos < (unsigned)CAP) slab[bb * CAP + lpos] = val;
            else perm[atomicAdd(&fill[bb], 1u)] = val;
        }
    } else {
        for (int li = tid; li < total; li += RB) {
            unsigned d = (unsigned)dst[base0 + li];
            unsigned s = (unsigned)src[base0 + li];
            unsigned bb = d >> W_SHIFT;
            unsigned val = s | ((d & (W - 1)) << 20);
            unsigned lpos = atomicAdd(&ptr[bb], 1u);
            if (lpos < (unsigned)CAP) slab[bb * CAP + lpos] = val;
            else perm[atomicAdd(&fill[bb], 1u)] = val;
        }
    }
    __syncthreads();
    if (tid < MAXB) {
        unsigned cnt = min(ptr[tid], (unsigned)CAP);
        gbase[tid] = cnt ? atomicAdd(&fill[tid], cnt) : 0u;
        ptr[tid] = cnt;
    }
    __syncthreads();
    for (int s = tid; s < MAXB * CAP; s += RB) {
        int bb = s / CAP;
        int i = s - bb * CAP;
        if (i < (int)ptr[bb]) perm[gbase[bb] + i] = slab[s];
    }
}

__global__ __launch_bounds__(AB) void k_dinv(const unsigned* __restrict__ perm,
                                             const unsigned* __restrict__ fill,
                                             const float2* __restrict__ x,
                                             float* __restrict__ dinv,
                                             unsigned* __restrict__ deg,
                                             __half2* __restrict__ xs,
                                             int N, unsigned C) {
    __shared__ unsigned c[2 * W];
    for (int i = threadIdx.x; i < 2 * W; i += AB) c[i] = 0u;
    __syncthreads();
    int b = blockIdx.x;
    unsigned par = threadIdx.x & 1u;
    unsigned s = (unsigned)b * C, e = fill[b];
    unsigned m = e - s, nv8 = m >> 3;
    const uv4* p4 = (const uv4*)(perm + s);
    for (unsigned j = threadIdx.x; j < nv8; j += AB) {
        uv4 qa = __builtin_nontemporal_load(p4 + 2u * j);
        uv4 qb = __builtin_nontemporal_load(p4 + 2u * j + 1u);
        atomicAdd(&c[((qa.x >> 20) << 1) | par], 1u);
        atomicAdd(&c[((qa.y >> 20) << 1) | par], 1u);
        atomicAdd(&c[((qa.z >> 20) << 1) | par], 1u);
        atomicAdd(&c[((qa.w >> 20) << 1) | par], 1u);
        atomicAdd(&c[((qb.x >> 20) << 1) | par], 1u);
        atomicAdd(&c[((qb.y >> 20) << 1) | par], 1u);
        atomicAdd(&c[((qb.z >> 20) << 1) | par], 1u);
        atomicAdd(&c[((qb.w >> 20) << 1) | par], 1u);
    }
    unsigned t = s + (nv8 << 3) + threadIdx.x;
    if (t < e) atomicAdd(&c[((perm[t] >> 20) << 1) | par], 1u);
    __syncthreads();
    int d0 = b << W_SHIFT;
    for (int l = threadIdx.x; l < W; l += AB) {
        int d = d0 + l;
        if (d < N) {
            unsigned cn = c[2 * l] + c[2 * l + 1];
            float dv = 1.0f / sqrtf((float)(cn + 1u));
            dinv[d] = dv;
            deg[d] = cn;
            float2 xv = x[d];
            xs[d] = __floats2half2_rn(xv.x * dv, xv.y * dv);
        }
    }
}

__global__ __launch_bounds__(AB) void k_acc1(const unsigned* __restrict__ perm,
                                             const unsigned* __restrict__ fill,
                                             const __half2* __restrict__ xs,
                                             const float* __restrict__ dinv,
                                             const unsigned* __restrict__ deg,
                                             const float* __restrict__ W1,
                                             const float* __restrict__ b1,
                                             const float* __restrict__ W2,
                                             __half2* __restrict__ h2s,
                                             int N, unsigned C) {
    __shared__ unsigned long long acc[2 * W];
    for (int i = threadIdx.x; i < 2 * W; i += AB) acc[i] = 0ull;
    __syncthreads();
    int b = blockIdx.x;
    unsigned par = threadIdx.x & 1u;
    unsigned s = (unsigned)b * C, e = fill[b];
    unsigned m = e - s, nv8 = m >> 3;
    const uv4* p4 = (const uv4*)(perm + s);
    for (unsigned j = threadIdx.x; j < nv8; j += AB) {
        uv4 qa = __builtin_nontemporal_load(p4 + 2u * j);
        uv4 qb = __builtin_nontemporal_load(p4 + 2u * j + 1u);
        float2 v0 = __half22float2(xs[qa.x & 0xFFFFFu]);
        float2 v1 = __half22float2(xs[qa.y & 0xFFFFFu]);
        float2 v2 = __half22float2(xs[qa.z & 0xFFFFFu]);
        float2 v3 = __half22float2(xs[qa.w & 0xFFFFFu]);
        float2 v4 = __half22float2(xs[qb.x & 0xFFFFFu]);
        float2 v5 = __half22float2(xs[qb.y & 0xFFFFFu]);
        float2 v6 = __half22float2(xs[qb.z & 0xFFFFFu]);
        float2 v7 = __half22float2(xs[qb.w & 0xFFFFFu]);
        atomicAdd(&acc[((qa.x >> 20) << 1) | par], pack2(v0.x, v0.y, SCALE1, BIAS1));
        atomicAdd(&acc[((qa.y >> 20) << 1) | par], pack2(v1.x, v1.y, SCALE1, BIAS1));
        atomicAdd(&acc[((qa.z >> 20) << 1) | par], pack2(v2.x, v2.y, SCALE1, BIAS1));
        atomicAdd(&acc[((qa.w >> 20) << 1) | par], pack2(v3.x, v3.y, SCALE1, BIAS1));
        atomicAdd(&acc[((qb.x >> 20) << 1) | par], pack2(v4.x, v4.y, SCALE1, BIAS1));
        atomicAdd(&acc[((qb.y >> 20) << 1) | par], pack2(v5.x, v5.y, SCALE1, BIAS1));
        atomicAdd(&acc[((qb.z >> 20) << 1) | par], pack2(v6.x, v6.y, SCALE1, BIAS1));
        atomicAdd(&acc[((qb.w >> 20) << 1) | par], pack2(v7.x, v7.y, SCALE1, BIAS1));
    }
    unsigned t = s + (nv8 << 3) + threadIdx.x;
    if (t < e) {
        unsigned p = perm[t];
        float2 v = __half22float2(xs[p & 0xFFFFFu]);
        atomicAdd(&acc[((p >> 20) << 1) | par], pack2(v.x, v.y, SCALE1, BIAS1));
    }
    __syncthreads();
    int d0 = b << W_SHIFT;
    float w10 = W1[0], w11 = W1[1], w12 = W1[2], w13 = W1[3];
    float w14 = W1[4], w15 = W1[5], w16 = W1[6], w17 = W1[7];
    float bb0 = b1[0], bb1 = b1[1], bb2 = b1[2], bb3 = b1[3];
    float u0 = W2[0], u1 = W2[1], u2 = W2[2], u3 = W2[3];
    float u4 = W2[4], u5 = W2[5], u6 = W2[6], u7 = W2[7];
    for (int l = threadIdx.x; l < W; l += AB) {
        int d = d0 + l;
        if (d < N) {
            float dv = dinv[d];
            unsigned cn = deg[d];
            unsigned long long a64 = acc[2 * l] + acc[2 * l + 1];
            unsigned lo = (unsigned)a64, hi = (unsigned)(a64 >> 32);
            float2 self = __half22float2(xs[d]);
            float Sx = (float)(int)(lo - cn * BIAS1) * INV1 + self.x;
            float Sy = (float)(int)(hi - cn * BIAS1) * INV1 + self.y;
            float a0 = fmaxf(fmaf(Sy, w14, Sx * w10) * dv + bb0, 0.0f);
            float a1 = fmaxf(fmaf(Sy, w15, Sx * w11) * dv + bb1, 0.0f);
            float a2 = fmaxf(fmaf(Sy, w16, Sx * w12) * dv + bb2, 0.0f);
            float a3 = fmaxf(fmaf(Sy, w17, Sx * w13) * dv + bb3, 0.0f);
            float hx = (a0 * u0 + a1 * u2 + a2 * u4 + a3 * u6) * dv;
            float hy = (a0 * u1 + a1 * u3 + a2 * u5 + a3 * u7) * dv;
            h2s[d] = __floats2half2_rn(hx, hy);
        }
    }
}

__global__ __launch_bounds__(AB) void k_acc2(const unsigned* __restrict__ perm,
                                             const unsigned* __restrict__ fill,
                                             const __half2* __restrict__ h2s,
                                             const float* __restrict__ dinv,
                                             const unsigned* __restrict__ deg,
                                             const float* __restrict__ b2,
                                             float2* __restrict__ out,
                                             int N, unsigned C) {
    __shared__ unsigned long long acc[2 * W];
    for (int i = threadIdx.x; i < 2 * W; i += AB) acc[i] = 0ull;
    __syncthreads();
    int b = blockIdx.x;
    unsigned par = threadIdx.x & 1u;
    unsigned s = (unsigned)b * C, e = fill[b];
    unsigned m = e - s, nv8 = m >> 3;
    const uv4* p4 = (const uv4*)(perm + s);
    for (unsigned j = threadIdx.x; j < nv8; j += AB) {
        uv4 qa = __builtin_nontemporal_load(p4 + 2u * j);
        uv4 qb = __builtin_nontemporal_load(p4 + 2u * j + 1u);
        float2 v0 = __half22float2(h2s[qa.x & 0xFFFFFu]);
        float2 v1 = __half22float2(h2s[qa.y & 0xFFFFFu]);
        float2 v2 = __half22float2(h2s[qa.z & 0xFFFFFu]);
        float2 v3 = __half22float2(h2s[qa.w & 0xFFFFFu]);
        float2 v4 = __half22float2(h2s[qb.x & 0xFFFFFu]);
        float2 v5 = __half22float2(h2s[qb.y & 0xFFFFFu]);
        float2 v6 = __half22float2(h2s[qb.z & 0xFFFFFu]);
        float2 v7 = __half22float2(h2s[qb.w & 0xFFFFFu]);
        atomicAdd(&acc[((qa.x >> 20) << 1) | par], pack2(v0.x, v0.y, SCALE2, BIAS2));
        atomicAdd(&acc[((qa.y >> 20) << 1) | par], pack2(v1.x, v1.y, SCALE2, BIAS2));
        atomicAdd(&acc[((qa.z >> 20) << 1) | par], pack2(v2.x, v2.y, SCALE2, BIAS2));
        atomicAdd(&acc[((qa.w >> 20) << 1) | par], pack2(v3.x, v3.y, SCALE2, BIAS2));
        atomicAdd(&acc[((qb.x >> 20) << 1) | par], pack2(v4.x, v4.y, SCALE2, BIAS2));
        atomicAdd(&acc[((qb.y >> 20) << 1) | par], pack2(v5.x, v5.y, SCALE2, BIAS2));
        atomicAdd(&acc[((qb.z >> 20) << 1) | par], pack2(v6.x, v6.y, SCALE2, BIAS2));
        atomicAdd(&acc[((qb.w >> 20) << 1) | par], pack2(v7.x, v7.y, SCALE2, BIAS2));
    }
    unsigned t = s + (nv8 << 3) + threadIdx.x;
    if (t < e) {
        unsigned p = perm[t];
        float2 v = __half22float2(h2s[p & 0xFFFFFu]);
        atomicAdd(&acc[((p >> 20) << 1) | par], pack2(v.x, v.y, SCALE2, BIAS2));
    }
    __syncthreads();
    int d0 = b << W_SHIFT;
    float bb0 = b2[0], bb1 = b2[1];
    for (int l = threadIdx.x; l < W; l += AB) {
        int d = d0 + l;
        if (d < N) {
            float dv = dinv[d];
            unsigned cn = deg[d];
            unsigned long long a64 = acc[2 * l] + acc[2 * l + 1];
            unsigned lo = (unsigned)a64, hi = (unsigned)(a64 >> 32);
            float2 v = __half22float2(h2s[d]);
            float Sx = (float)(int)(lo - cn * BIAS2) * INV2 + v.x;
            float Sy = (float)(int)(hi - cn * BIAS2) * INV2 + v.y;
            out[d] = make_float2(Sx * dv + bb0, Sy * dv + bb1);
        }
    }
}

// ---------------- tier 3 fallback (R1-style) ----------

__global__ __launch_bounds__(256) void f_init_deg(unsigned* deg, int n) {
    int i = blockIdx.x * 256 + threadIdx.x;
    if (i < n) deg[i] = 1u;
}
__global__ __launch_bounds__(256) void f_count_deg(const int* dst, unsigned* deg, int E) {
    int e = blockIdx.x * 256 + threadIdx.x;
    if (e < E) atomicAdd(&deg[dst[e]], 1u);
}
__global__ __launch_bounds__(256) void f_node1(const float2* x, const float* W1,
                                               const unsigned* deg, float* dinv,
                                               float4* h1s, float4* agg1, int n) {
    int i = blockIdx.x * 256 + threadIdx.x;
    if (i >= n) return;
    float dv = 1.0f / sqrtf((float)deg[i]);
    dinv[i] = dv;
    float2 xv = x[i];
    float4 h;
    h.x = fmaf(xv.y, W1[4], xv.x * W1[0]) * dv;
    h.y = fmaf(xv.y, W1[5], xv.x * W1[1]) * dv;
    h.z = fmaf(xv.y, W1[6], xv.x * W1[2]) * dv;
    h.w = fmaf(xv.y, W1[7], xv.x * W1[3]) * dv;
    h1s[i] = h;
    agg1[i] = make_float4(h.x * dv, h.y * dv, h.z * dv, h.w * dv);
}
__global__ __launch_bounds__(256) void f_edge1(const int* src, const int* dst,
                                               const float* dinv, const float4* h1s,
                                               float* agg1, int E) {
    int e = blockIdx.x * 256 + threadIdx.x;
    if (e >= E) return;
    int s = src[e], d = dst[e];
    float w = dinv[d];
    float4 m = h1s[s];
    float* p = agg1 + 4ll * d;
    unsafeAtomicAdd(p + 0, m.x * w);
    unsafeAtomicAdd(p + 1, m.y * w);
    unsafeAtomicAdd(p + 2, m.z * w);
    unsafeAtomicAdd(p + 3, m.w * w);
}
__global__ __launch_bounds__(256) void f_node2(const float4* agg1, const float* b1,
                                               const float* W2, const float* b2,
                                               const float* dinv, float2* h2s,
                                               float2* out, int n) {
    int i = blockIdx.x * 256 + threadIdx.x;
    if (i >= n) return;
    float4 a = agg1[i];
    a.x = fmaxf(a.x + b1[0], 0.0f);
    a.y = fmaxf(a.y + b1[1], 0.0f);
    a.z = fmaxf(a.z + b1[2], 0.0f);
    a.w = fmaxf(a.w + b1[3], 0.0f);
    float dv = dinv[i];
    float2 h;
    h.x = (a.x * W2[0] + a.y * W2[2] + a.z * W2[4] + a.w * W2[6]) * dv;
    h.y = (a.x * W2[1] + a.y * W2[3] + a.z * W2[5] + a.w * W2[7]) * dv;
    h2s[i] = h;
    out[i] = make_float2(b2[0] + h.x * dv, b2[1] + h.y * dv);
}
__global__ __launch_bounds__(256) void f_edge2(const int* src, const int* dst,
                                               const float* dinv, const float2* h2s,
                                               float* out, int E) {
    int e = blockIdx.x * 256 + threadIdx.x;
    if (e >= E) return;
    int s = src[e], d = dst[e];
    float w = dinv[d];
    float2 m = h2s[s];
    float* p = out + 2ll * d;
    unsafeAtomicAdd(p + 0, m.x * w);
    unsafeAtomicAdd(p + 1, m.y * w);
}

extern "C" void kernel_launch(void* const* d_in, const int* in_sizes, int n_in,
                              void* d_out, int out_size, void* d_ws, size_t ws_size,
                              hipStream_t stream) {
    const float* x  = (const float*)d_in[0];
    const int* ei   = (const int*)d_in[1];
    const float* W1 = (const float*)d_in[2];
    const float* b1 = (const float*)d_in[3];
    const float* W2 = (const float*)d_in[4];
    const float* b2 = (const float*)d_in[5];
    float* out = (float*)d_out;

    const int N = in_sizes[0] / 2;
    const int E = in_sizes[1] / 2;
    const int* src = ei;
    const int* dst = ei + E;
    const int NB = (N + W - 1) >> W_SHIFT;
    const int NCH = (E + CHUNK - 1) / CHUNK;

    char* ws = (char*)d_ws;
    const int gN = (N + 255) / 256;
    const int gE = (E + 255) / 256;
    const long Cmin = (long)(E / (NB > 0 ? NB : 1)) + 4096;

    // ---- tier 1: single cooperative kernel ----
    size_t fixedc = 32768 + (size_t)12 * N;   // fill | deg | xs | h2s
    long availc = (long)ws_size - (long)fixedc;
    long Cmaxc = (availc > 0) ? availc / (4L * NB) : 0;
    long Cwc = (Cmaxc > Cmin + 8192) ? (Cmin + 8192) : Cmaxc;
    unsigned Cc = (unsigned)(Cwc & ~7L);
    bool coop = ((long)Cc >= Cmin) && (NB <= MAXB) && (N <= (1 << 20)) && (E > 0);

    // ---- tier 2: R12 multi-kernel ----
    size_t fixed = 32768 + (size_t)16 * N;    // fill | dinv | deg | xs | h2s
    long avail = (long)ws_size - (long)fixed;
    long Cmax = (avail > 0) ? avail / (4L * NB) : 0;
    long Cw = (Cmax > Cmin + 8192) ? (Cmin + 8192) : Cmax;
    unsigned C = (unsigned)(Cw & ~7L);
    bool fast = ((long)C >= Cmin) && (NB <= MAXB) && (N <= (1 << 20));

    if (coop) {
        unsigned* fill = (unsigned*)ws;
        unsigned* deg  = (unsigned*)(ws + 32768);
        __half2*  xs   = (__half2*)(ws + 32768 + (size_t)4 * N);
        __half2*  h2s  = (__half2*)(ws + 32768 + (size_t)8 * N);
        unsigned* perm = (unsigned*)(ws + fixedc);
        const float2* xp = (const float2*)x;
        float2* outp = (float2*)out;
        int Nv = N, Ev = E, NBv = NB, NCHv = NCH;
        unsigned Cv = Cc;
        void* args[] = {
            (void*)&src, (void*)&dst, (void*)&xp,
            (void*)&W1, (void*)&b1, (void*)&W2, (void*)&b2,
            (void*)&fill, (void*)&deg, (void*)&xs, (void*)&h2s,
            (void*)&outp, (void*)&perm,
            (void*)&Nv, (void*)&Ev, (void*)&Cv, (void*)&NBv, (void*)&NCHv
        };
        hipLaunchCooperativeKernel((const void*)k_fused, dim3(NB), dim3(CT),
                                   args, 0u, stream);
    } else if (fast) {
        unsigned* fill = (unsigned*)(ws);
        float*    dinv = (float*)(ws + 32768);
        unsigned* deg  = (unsigned*)(ws + 32768 + (size_t)4 * N);
        __half2*  xs   = (__half2*)(ws + 32768 + (size_t)8 * N);
        __half2*  h2s  = (__half2*)(ws + 32768 + (size_t)12 * N);
        unsigned* perm = (unsigned*)(ws + fixed);

        k_zero_fill<<<(NB + 255) / 256, 256, 0, stream>>>(fill, NB, C);
        k_reorder<<<(E + CHUNK - 1) / CHUNK, RB, 0, stream>>>(src, dst, fill, perm, E);
        k_dinv<<<NB, AB, 0, stream>>>(perm, fill, (const float2*)x, dinv, deg, xs, N, C);
        k_acc1<<<NB, AB, 0, stream>>>(perm, fill, xs, dinv, deg, W1, b1, W2, h2s, N, C);
        k_acc2<<<NB, AB, 0, stream>>>(perm, fill, h2s, dinv, deg, b2, (float2*)out, N, C);
    } else {
        unsigned* deg = (unsigned*)(ws);
        float* dinv   = (float*)(ws + (size_t)4 * N);
        float* h1s    = (float*)(ws + (size_t)8 * N);
        float* agg1   = (float*)(ws + (size_t)24 * N);
        float* h2s    = h1s;

        f_init_deg<<<gN, 256, 0, stream>>>(deg, N);
        f_count_deg<<<gE, 256, 0, stream>>>(dst, deg, E);
        f_node1<<<gN, 256, 0, stream>>>((const float2*)x, W1, deg, dinv,
                                        (float4*)h1s, (float4*)agg1, N);
        f_edge1<<<gE, 256, 0, stream>>>(src, dst, dinv, (const float4*)h1s, agg1, E);
        f_node2<<<gN, 256, 0, stream>>>((const float4*)agg1, b1, W2, b2, dinv,
                                        (float2*)h2s, (float2*)out, N);
        f_edge2<<<gE, 256, 0, stream>>>(src, dst, dinv, (const float2*)h2s, out, E);
    }
}

// Round 6
// 440.200 us; speedup vs baseline: 2.2693x; 2.2693x over previous
//
#include <hip/hip_runtime.h>
#include <hip/hip_fp16.h>

// GCN 2-layer forward, MI355X. R17: ds_pk_add_f16 accumulators.
// R16 post-mortem: cooperative fusion = +500us (grid.sync over 489 blocks
// with cross-XCD L2 flush per phase; 852us fused vs ~356us of phase work).
// LESSON: on MI355X, launch gaps (~15us) are near-optimal global sync;
// never replace them with grid.sync when phases exchange global data.
// R17 lever (pre-committed in R16): the two 94us u64-LDS-atomic towers.
// Measured: u32-class LDS atomic ~1.8cyc/edge, u64 ~3.5. gfx950 has
// ds_pk_add_f16 (packed 2xfp16 add, u32 size class). Accs now feed the
// gathered __half2 DIRECTLY into unsafeAtomicAdd on a __shared__ __half2
// (lowers to ds_pk_add_f16), x4-replicated (same 16B/dst footprint as
// 2x u64). Fixed-point pack/bias VALU work deleted; deg array deleted.
// Precision: per-replica fp16 chains ~4 adds, epilogue *dv (~0.2)
// attenuates -> ~2e-4 added error vs current absmax 9.8e-4.
// Falsifiers: accs>=85us -> pk at u64 rate, revert, ~431 is roofline;
// bench fail -> precision/lowering, revert to R12.
// Pipeline: zero_fill, reorder(slab), dinv(+xs), acc1(pk,+MLP), acc2(pk).

constexpr int W_SHIFT = 11;
constexpr int W = 2048;            // nodes per dst window
constexpr int MAXB = 512;          // max buckets/windows
constexpr int RB = 1024;           // reorder block threads
constexpr int CHUNK = 8192;        // edges per reorder block
constexpr int CAP = 28;            // reorder slab capacity per bucket
constexpr int AB = 512;            // accumulate block threads

typedef unsigned uv4 __attribute__((ext_vector_type(4)));
typedef int      iv4 __attribute__((ext_vector_type(4)));

__global__ __launch_bounds__(256) void k_zero_fill(unsigned* __restrict__ fill,
                                                   int nb, unsigned C) {
    int i = blockIdx.x * 256 + threadIdx.x;
    if (i < nb) fill[i] = (unsigned)i * C;
}

// Slab multisplit: single u32 LDS atomic per edge (R12, measured-good).
__global__ __launch_bounds__(RB) void k_reorder(const int* __restrict__ src,
                                                const int* __restrict__ dst,
                                                unsigned* __restrict__ fill,
                                                unsigned* __restrict__ perm, int E) {
    __shared__ unsigned slab[MAXB * CAP];  // 57344 B
    __shared__ unsigned ptr[MAXB];
    __shared__ unsigned gbase[MAXB];
    int tid = threadIdx.x;
    if (tid < MAXB) ptr[tid] = 0u;
    __syncthreads();
    long base0 = (long)blockIdx.x * CHUNK;
    int total = (int)min((long)CHUNK, (long)E - base0);
    bool full = (total == CHUNK);

    if (full) {
        const iv4* dv4 = (const iv4*)(dst + base0);
        const iv4* sv4 = (const iv4*)(src + base0);
        #pragma unroll
        for (int k = 0; k < 2; k++) {
            iv4 dq = dv4[k * RB + tid];
            iv4 sq = sv4[k * RB + tid];
            unsigned d, b, val, lpos;
            d = (unsigned)dq.x; b = d >> W_SHIFT;
            val = (unsigned)sq.x | ((d & (W - 1)) << 20);
            lpos = atomicAdd(&ptr[b], 1u);
            if (lpos < (unsigned)CAP) slab[b * CAP + lpos] = val;
            else perm[atomicAdd(&fill[b], 1u)] = val;
            d = (unsigned)dq.y; b = d >> W_SHIFT;
            val = (unsigned)sq.y | ((d & (W - 1)) << 20);
            lpos = atomicAdd(&ptr[b], 1u);
            if (lpos < (unsigned)CAP) slab[b * CAP + lpos] = val;
            else perm[atomicAdd(&fill[b], 1u)] = val;
            d = (unsigned)dq.z; b = d >> W_SHIFT;
            val = (unsigned)sq.z | ((d & (W - 1)) << 20);
            lpos = atomicAdd(&ptr[b], 1u);
            if (lpos < (unsigned)CAP) slab[b * CAP + lpos] = val;
            else perm[atomicAdd(&fill[b], 1u)] = val;
            d = (unsigned)dq.w; b = d >> W_SHIFT;
            val = (unsigned)sq.w | ((d & (W - 1)) << 20);
            lpos = atomicAdd(&ptr[b], 1u);
            if (lpos < (unsigned)CAP) slab[b * CAP + lpos] = val;
            else perm[atomicAdd(&fill[b], 1u)] = val;
        }
    } else {
        for (int li = tid; li < total; li += RB) {
            unsigned d = (unsigned)dst[base0 + li];
            unsigned s = (unsigned)src[base0 + li];
            unsigned b = d >> W_SHIFT;
            unsigned val = s | ((d & (W - 1)) << 20);
            unsigned lpos = atomicAdd(&ptr[b], 1u);
            if (lpos < (unsigned)CAP) slab[b * CAP + lpos] = val;
            else perm[atomicAdd(&fill[b], 1u)] = val;
        }
    }
    __syncthreads();
    if (tid < MAXB) {
        unsigned cnt = min(ptr[tid], (unsigned)CAP);
        gbase[tid] = cnt ? atomicAdd(&fill[tid], cnt) : 0u;
        ptr[tid] = cnt;
    }
    __syncthreads();
    for (int s = tid; s < MAXB * CAP; s += RB) {
        int b = s / CAP;
        int i = s - b * CAP;
        if (i < (int)ptr[b]) perm[gbase[b] + i] = slab[s];
    }
}

// degree count (x2-replicated u32 histogram) -> dinv + xs
__global__ __launch_bounds__(AB) void k_dinv(const unsigned* __restrict__ perm,
                                             const unsigned* __restrict__ fill,
                                             const float2* __restrict__ x,
                                             float* __restrict__ dinv,
                                             __half2* __restrict__ xs,
                                             int N, unsigned C) {
    __shared__ unsigned c[2 * W];
    for (int i = threadIdx.x; i < 2 * W; i += AB) c[i] = 0u;
    __syncthreads();
    int b = blockIdx.x;
    unsigned par = threadIdx.x & 1u;
    unsigned s = (unsigned)b * C, e = fill[b];
    unsigned m = e - s, nv8 = m >> 3;
    const uv4* p4 = (const uv4*)(perm + s);
    for (unsigned j = threadIdx.x; j < nv8; j += AB) {
        uv4 qa = __builtin_nontemporal_load(p4 + 2u * j);
        uv4 qb = __builtin_nontemporal_load(p4 + 2u * j + 1u);
        atomicAdd(&c[((qa.x >> 20) << 1) | par], 1u);
        atomicAdd(&c[((qa.y >> 20) << 1) | par], 1u);
        atomicAdd(&c[((qa.z >> 20) << 1) | par], 1u);
        atomicAdd(&c[((qa.w >> 20) << 1) | par], 1u);
        atomicAdd(&c[((qb.x >> 20) << 1) | par], 1u);
        atomicAdd(&c[((qb.y >> 20) << 1) | par], 1u);
        atomicAdd(&c[((qb.z >> 20) << 1) | par], 1u);
        atomicAdd(&c[((qb.w >> 20) << 1) | par], 1u);
    }
    unsigned t = s + (nv8 << 3) + threadIdx.x;
    if (t < e) atomicAdd(&c[((perm[t] >> 20) << 1) | par], 1u);
    __syncthreads();
    int d0 = b << W_SHIFT;
    for (int l = threadIdx.x; l < W; l += AB) {
        int d = d0 + l;
        if (d < N) {
            unsigned cn = c[2 * l] + c[2 * l + 1];
            float dv = 1.0f / sqrtf((float)(cn + 1u));  // +1 self-loop
            dinv[d] = dv;
            float2 xv = x[d];
            xs[d] = __floats2half2_rn(xv.x * dv, xv.y * dv);
        }
    }
}

// layer1: 1x ds_pk_add_f16 per edge (x4-replicated half2 acc) + full MLP
__global__ __launch_bounds__(AB) void k_acc1(const unsigned* __restrict__ perm,
                                             const unsigned* __restrict__ fill,
                                             const __half2* __restrict__ xs,
                                             const float* __restrict__ dinv,
                                             const float* __restrict__ W1,
                                             const float* __restrict__ b1,
                                             const float* __restrict__ W2,
                                             __half2* __restrict__ h2s,
                                             int N, unsigned C) {
    __shared__ __half2 acc[4 * W];            // x4 replicas, 32 KB
    for (int i = threadIdx.x; i < 4 * W; i += AB)
        ((unsigned*)acc)[i] = 0u;
    __syncthreads();
    int b = blockIdx.x;
    unsigned par = threadIdx.x & 3u;
    unsigned s = (unsigned)b * C, e = fill[b];
    unsigned m = e - s, nv8 = m >> 3;
    const uv4* p4 = (const uv4*)(perm + s);
    for (unsigned j = threadIdx.x; j < nv8; j += AB) {
        uv4 qa = __builtin_nontemporal_load(p4 + 2u * j);
        uv4 qb = __builtin_nontemporal_load(p4 + 2u * j + 1u);
        __half2 v0 = xs[qa.x & 0xFFFFFu];
        __half2 v1 = xs[qa.y & 0xFFFFFu];
        __half2 v2 = xs[qa.z & 0xFFFFFu];
        __half2 v3 = xs[qa.w & 0xFFFFFu];
        __half2 v4 = xs[qb.x & 0xFFFFFu];
        __half2 v5 = xs[qb.y & 0xFFFFFu];
        __half2 v6 = xs[qb.z & 0xFFFFFu];
        __half2 v7 = xs[qb.w & 0xFFFFFu];
        unsafeAtomicAdd(&acc[((qa.x >> 20) << 2) | par], v0);
        unsafeAtomicAdd(&acc[((qa.y >> 20) << 2) | par], v1);
        unsafeAtomicAdd(&acc[((qa.z >> 20) << 2) | par], v2);
        unsafeAtomicAdd(&acc[((qa.w >> 20) << 2) | par], v3);
        unsafeAtomicAdd(&acc[((qb.x >> 20) << 2) | par], v4);
        unsafeAtomicAdd(&acc[((qb.y >> 20) << 2) | par], v5);
        unsafeAtomicAdd(&acc[((qb.z >> 20) << 2) | par], v6);
        unsafeAtomicAdd(&acc[((qb.w >> 20) << 2) | par], v7);
    }
    unsigned t = s + (nv8 << 3) + threadIdx.x;
    if (t < e) {
        unsigned p = perm[t];
        unsafeAtomicAdd(&acc[((p >> 20) << 2) | par], xs[p & 0xFFFFFu]);
    }
    __syncthreads();
    int d0 = b << W_SHIFT;
    float w10 = W1[0], w11 = W1[1], w12 = W1[2], w13 = W1[3];
    float w14 = W1[4], w15 = W1[5], w16 = W1[6], w17 = W1[7];
    float bb0 = b1[0], bb1 = b1[1], bb2 = b1[2], bb3 = b1[3];
    float u0 = W2[0], u1 = W2[1], u2 = W2[2], u3 = W2[3];
    float u4 = W2[4], u5 = W2[5], u6 = W2[6], u7 = W2[7];
    for (int l = threadIdx.x; l < W; l += AB) {
        int d = d0 + l;
        if (d < N) {
            float dv = dinv[d];
            float2 r0 = __half22float2(acc[4 * l]);
            float2 r1 = __half22float2(acc[4 * l + 1]);
            float2 r2 = __half22float2(acc[4 * l + 2]);
            float2 r3 = __half22float2(acc[4 * l + 3]);
            float2 self = __half22float2(xs[d]);
            float Sx = (r0.x + r1.x) + (r2.x + r3.x) + self.x;
            float Sy = (r0.y + r1.y) + (r2.y + r3.y) + self.y;
            float a0 = fmaxf(fmaf(Sy, w14, Sx * w10) * dv + bb0, 0.0f);
            float a1 = fmaxf(fmaf(Sy, w15, Sx * w11) * dv + bb1, 0.0f);
            float a2 = fmaxf(fmaf(Sy, w16, Sx * w12) * dv + bb2, 0.0f);
            float a3 = fmaxf(fmaf(Sy, w17, Sx * w13) * dv + bb3, 0.0f);
            float hx = (a0 * u0 + a1 * u2 + a2 * u4 + a3 * u6) * dv;
            float hy = (a0 * u1 + a1 * u3 + a2 * u5 + a3 * u7) * dv;
            h2s[d] = __floats2half2_rn(hx, hy);
        }
    }
}

// layer2: 1x ds_pk_add_f16 per edge + bias epilogue
__global__ __launch_bounds__(AB) void k_acc2(const unsigned* __restrict__ perm,
                                             const unsigned* __restrict__ fill,
                                             const __half2* __restrict__ h2s,
                                             const float* __restrict__ dinv,
                                             const float* __restrict__ b2,
                                             float2* __restrict__ out,
                                             int N, unsigned C) {
    __shared__ __half2 acc[4 * W];            // x4 replicas, 32 KB
    for (int i = threadIdx.x; i < 4 * W; i += AB)
        ((unsigned*)acc)[i] = 0u;
    __syncthreads();
    int b = blockIdx.x;
    unsigned par = threadIdx.x & 3u;
    unsigned s = (unsigned)b * C, e = fill[b];
    unsigned m = e - s, nv8 = m >> 3;
    const uv4* p4 = (const uv4*)(perm + s);
    for (unsigned j = threadIdx.x; j < nv8; j += AB) {
        uv4 qa = __builtin_nontemporal_load(p4 + 2u * j);
        uv4 qb = __builtin_nontemporal_load(p4 + 2u * j + 1u);
        __half2 v0 = h2s[qa.x & 0xFFFFFu];
        __half2 v1 = h2s[qa.y & 0xFFFFFu];
        __half2 v2 = h2s[qa.z & 0xFFFFFu];
        __half2 v3 = h2s[qa.w & 0xFFFFFu];
        __half2 v4 = h2s[qb.x & 0xFFFFFu];
        __half2 v5 = h2s[qb.y & 0xFFFFFu];
        __half2 v6 = h2s[qb.z & 0xFFFFFu];
        __half2 v7 = h2s[qb.w & 0xFFFFFu];
        unsafeAtomicAdd(&acc[((qa.x >> 20) << 2) | par], v0);
        unsafeAtomicAdd(&acc[((qa.y >> 20) << 2) | par], v1);
        unsafeAtomicAdd(&acc[((qa.z >> 20) << 2) | par], v2);
        unsafeAtomicAdd(&acc[((qa.w >> 20) << 2) | par], v3);
        unsafeAtomicAdd(&acc[((qb.x >> 20) << 2) | par], v4);
        unsafeAtomicAdd(&acc[((qb.y >> 20) << 2) | par], v5);
        unsafeAtomicAdd(&acc[((qb.z >> 20) << 2) | par], v6);
        unsafeAtomicAdd(&acc[((qb.w >> 20) << 2) | par], v7);
    }
    unsigned t = s + (nv8 << 3) + threadIdx.x;
    if (t < e) {
        unsigned p = perm[t];
        unsafeAtomicAdd(&acc[((p >> 20) << 2) | par], h2s[p & 0xFFFFFu]);
    }
    __syncthreads();
    int d0 = b << W_SHIFT;
    float bb0 = b2[0], bb1 = b2[1];
    for (int l = threadIdx.x; l < W; l += AB) {
        int d = d0 + l;
        if (d < N) {
            float dv = dinv[d];
            float2 r0 = __half22float2(acc[4 * l]);
            float2 r1 = __half22float2(acc[4 * l + 1]);
            float2 r2 = __half22float2(acc[4 * l + 2]);
            float2 r3 = __half22float2(acc[4 * l + 3]);
            float2 self = __half22float2(h2s[d]);
            float Sx = (r0.x + r1.x) + (r2.x + r3.x) + self.x;
            float Sy = (r0.y + r1.y) + (r2.y + r3.y) + self.y;
            out[d] = make_float2(Sx * dv + bb0, Sy * dv + bb1);
        }
    }
}

// ---------------- fallback (R1-style, only if workspace too small) ----------

__global__ __launch_bounds__(256) void f_init_deg(unsigned* deg, int n) {
    int i = blockIdx.x * 256 + threadIdx.x;
    if (i < n) deg[i] = 1u;
}
__global__ __launch_bounds__(256) void f_count_deg(const int* dst, unsigned* deg, int E) {
    int e = blockIdx.x * 256 + threadIdx.x;
    if (e < E) atomicAdd(&deg[dst[e]], 1u);
}
__global__ __launch_bounds__(256) void f_node1(const float2* x, const float* W1,
                                               const unsigned* deg, float* dinv,
                                               float4* h1s, float4* agg1, int n) {
    int i = blockIdx.x * 256 + threadIdx.x;
    if (i >= n) return;
    float dv = 1.0f / sqrtf((float)deg[i]);
    dinv[i] = dv;
    float2 xv = x[i];
    float4 h;
    h.x = fmaf(xv.y, W1[4], xv.x * W1[0]) * dv;
    h.y = fmaf(xv.y, W1[5], xv.x * W1[1]) * dv;
    h.z = fmaf(xv.y, W1[6], xv.x * W1[2]) * dv;
    h.w = fmaf(xv.y, W1[7], xv.x * W1[3]) * dv;
    h1s[i] = h;
    agg1[i] = make_float4(h.x * dv, h.y * dv, h.z * dv, h.w * dv);
}
__global__ __launch_bounds__(256) void f_edge1(const int* src, const int* dst,
                                               const float* dinv, const float4* h1s,
                                               float* agg1, int E) {
    int e = blockIdx.x * 256 + threadIdx.x;
    if (e >= E) return;
    int s = src[e], d = dst[e];
    float w = dinv[d];
    float4 m = h1s[s];
    float* p = agg1 + 4ll * d;
    unsafeAtomicAdd(p + 0, m.x * w);
    unsafeAtomicAdd(p + 1, m.y * w);
    unsafeAtomicAdd(p + 2, m.z * w);
    unsafeAtomicAdd(p + 3, m.w * w);
}
__global__ __launch_bounds__(256) void f_node2(const float4* agg1, const float* b1,
                                               const float* W2, const float* b2,
                                               const float* dinv, float2* h2s,
                                               float2* out, int n) {
    int i = blockIdx.x * 256 + threadIdx.x;
    if (i >= n) return;
    float4 a = agg1[i];
    a.x = fmaxf(a.x + b1[0], 0.0f);
    a.y = fmaxf(a.y + b1[1], 0.0f);
    a.z = fmaxf(a.z + b1[2], 0.0f);
    a.w = fmaxf(a.w + b1[3], 0.0f);
    float dv = dinv[i];
    float2 h;
    h.x = (a.x * W2[0] + a.y * W2[2] + a.z * W2[4] + a.w * W2[6]) * dv;
    h.y = (a.x * W2[1] + a.y * W2[3] + a.z * W2[5] + a.w * W2[7]) * dv;
    h2s[i] = h;
    out[i] = make_float2(b2[0] + h.x * dv, b2[1] + h.y * dv);
}
__global__ __launch_bounds__(256) void f_edge2(const int* src, const int* dst,
                                               const float* dinv, const float2* h2s,
                                               float* out, int E) {
    int e = blockIdx.x * 256 + threadIdx.x;
    if (e >= E) return;
    int s = src[e], d = dst[e];
    float w = dinv[d];
    float2 m = h2s[s];
    float* p = out + 2ll * d;
    unsafeAtomicAdd(p + 0, m.x * w);
    unsafeAtomicAdd(p + 1, m.y * w);
}

extern "C" void kernel_launch(void* const* d_in, const int* in_sizes, int n_in,
                              void* d_out, int out_size, void* d_ws, size_t ws_size,
                              hipStream_t stream) {
    const float* x  = (const float*)d_in[0];
    const int* ei   = (const int*)d_in[1];
    const float* W1 = (const float*)d_in[2];
    const float* b1 = (const float*)d_in[3];
    const float* W2 = (const float*)d_in[4];
    const float* b2 = (const float*)d_in[5];
    float* out = (float*)d_out;

    const int N = in_sizes[0] / 2;
    const int E = in_sizes[1] / 2;
    const int* src = ei;
    const int* dst = ei + E;
    const int NB = (N + W - 1) >> W_SHIFT;

    char* ws = (char*)d_ws;
    const int gN = (N + 255) / 256;
    const int gE = (E + 255) / 256;

    // slab capacity: mean fill E/NB (~32.7K, sigma~181); margin 4096 (>20σ)
    size_t fixed = 32768 + (size_t)12 * N;   // fill | dinv | xs | h2s
    long avail = (long)ws_size - (long)fixed;
    long Cmax = (avail > 0) ? avail / (4L * NB) : 0;
    long Cmin = (long)(E / (NB > 0 ? NB : 1)) + 4096;
    long Cw = (Cmax > Cmin + 8192) ? (Cmin + 8192) : Cmax;
    unsigned C = (unsigned)(Cw & ~7L);       // multiple of 8 for uint4x2 loads
    bool fast = ((long)C >= Cmin) && (NB <= MAXB) && (N <= (1 << 20));

    if (fast) {
        unsigned* fill = (unsigned*)(ws);                          // NB entries
        float*    dinv = (float*)(ws + 32768);
        __half2*  xs   = (__half2*)(ws + 32768 + (size_t)4 * N);
        __half2*  h2s  = (__half2*)(ws + 32768 + (size_t)8 * N);
        unsigned* perm = (unsigned*)(ws + fixed);

        k_zero_fill<<<(NB + 255) / 256, 256, 0, stream>>>(fill, NB, C);
        k_reorder<<<(E + CHUNK - 1) / CHUNK, RB, 0, stream>>>(src, dst, fill, perm, E);
        k_dinv<<<NB, AB, 0, stream>>>(perm, fill, (const float2*)x, dinv, xs, N, C);
        k_acc1<<<NB, AB, 0, stream>>>(perm, fill, xs, dinv, W1, b1, W2, h2s, N, C);
        k_acc2<<<NB, AB, 0, stream>>>(perm, fill, h2s, dinv, b2, (float2*)out, N, C);
    } else {
        unsigned* deg = (unsigned*)(ws);
        float* dinv   = (float*)(ws + (size_t)4 * N);
        float* h1s    = (float*)(ws + (size_t)8 * N);
        float* agg1   = (float*)(ws + (size_t)24 * N);
        float* h2s    = h1s;

        f_init_deg<<<gN, 256, 0, stream>>>(deg, N);
        f_count_deg<<<gE, 256, 0, stream>>>(dst, deg, E);
        f_node1<<<gN, 256, 0, stream>>>((const float2*)x, W1, deg, dinv,
                                        (float4*)h1s, (float4*)agg1, N);
        f_edge1<<<gE, 256, 0, stream>>>(src, dst, dinv, (const float4*)h1s, agg1, E);
        f_node2<<<gN, 256, 0, stream>>>((const float4*)agg1, b1, W2, b2, dinv,
                                        (float2*)h2s, (float2*)out, N);
        f_edge2<<<gE, 256, 0, stream>>>(src, dst, dinv, (const float2*)h2s, out, E);
    }
}

// Round 7
// 435.934 us; speedup vs baseline: 2.2915x; 1.0098x over previous
//
#include <hip/hip_runtime.h>
#include <hip/hip_fp16.h>

// GCN 2-layer forward, MI355X. R18: double per-CU memory concurrency.
// R17 post-mortem: pass time invariant to atomic width (u64 94us vs pk16
// 97us), bank conflicts (1.9M vs 0), VALU, and atomic-vs-gather (R14: 103).
// All pipes idle (VALU 3.3%, HBM 9%) => Little's-Law latency bound:
// 8 waves/block x 8 gathers in flight x 2 blocks/CU = 128 outstanding,
// / ~450cyc L2 latency = 0.28 edges/cyc = 3.5 cyc/edge (matches).
// The "atomic floor" of R5-R17 was a misattribution.
// R18: AB 512 -> 1024 for dinv/acc1/acc2. 2 blocks/CU still resident
// (64KB LDS, 2048 thr = 32 waves max, VGPR 16) => 256 outstanding/CU.
// Falsifier: accs >= 85us at 32 waves/CU => contention floor, ~431 is
// the roofline (declare next round).
// Pipeline: zero_fill, reorder(slab), dinv(+xs), acc1(pk,+MLP), acc2(pk).

constexpr int W_SHIFT = 11;
constexpr int W = 2048;            // nodes per dst window
constexpr int MAXB = 512;          // max buckets/windows
constexpr int RB = 1024;           // reorder block threads
constexpr int CHUNK = 8192;        // edges per reorder block
constexpr int CAP = 28;            // reorder slab capacity per bucket
constexpr int AB = 1024;           // accumulate block threads (R18: 512->1024)

typedef unsigned uv4 __attribute__((ext_vector_type(4)));
typedef int      iv4 __attribute__((ext_vector_type(4)));

__global__ __launch_bounds__(256) void k_zero_fill(unsigned* __restrict__ fill,
                                                   int nb, unsigned C) {
    int i = blockIdx.x * 256 + threadIdx.x;
    if (i < nb) fill[i] = (unsigned)i * C;
}

// Slab multisplit: single u32 LDS atomic per edge (R12, measured-good).
__global__ __launch_bounds__(RB) void k_reorder(const int* __restrict__ src,
                                                const int* __restrict__ dst,
                                                unsigned* __restrict__ fill,
                                                unsigned* __restrict__ perm, int E) {
    __shared__ unsigned slab[MAXB * CAP];  // 57344 B
    __shared__ unsigned ptr[MAXB];
    __shared__ unsigned gbase[MAXB];
    int tid = threadIdx.x;
    if (tid < MAXB) ptr[tid] = 0u;
    __syncthreads();
    long base0 = (long)blockIdx.x * CHUNK;
    int total = (int)min((long)CHUNK, (long)E - base0);
    bool full = (total == CHUNK);

    if (full) {
        const iv4* dv4 = (const iv4*)(dst + base0);
        const iv4* sv4 = (const iv4*)(src + base0);
        #pragma unroll
        for (int k = 0; k < 2; k++) {
            iv4 dq = dv4[k * RB + tid];
            iv4 sq = sv4[k * RB + tid];
            unsigned d, b, val, lpos;
            d = (unsigned)dq.x; b = d >> W_SHIFT;
            val = (unsigned)sq.x | ((d & (W - 1)) << 20);
            lpos = atomicAdd(&ptr[b], 1u);
            if (lpos < (unsigned)CAP) slab[b * CAP + lpos] = val;
            else perm[atomicAdd(&fill[b], 1u)] = val;
            d = (unsigned)dq.y; b = d >> W_SHIFT;
            val = (unsigned)sq.y | ((d & (W - 1)) << 20);
            lpos = atomicAdd(&ptr[b], 1u);
            if (lpos < (unsigned)CAP) slab[b * CAP + lpos] = val;
            else perm[atomicAdd(&fill[b], 1u)] = val;
            d = (unsigned)dq.z; b = d >> W_SHIFT;
            val = (unsigned)sq.z | ((d & (W - 1)) << 20);
            lpos = atomicAdd(&ptr[b], 1u);
            if (lpos < (unsigned)CAP) slab[b * CAP + lpos] = val;
            else perm[atomicAdd(&fill[b], 1u)] = val;
            d = (unsigned)dq.w; b = d >> W_SHIFT;
            val = (unsigned)sq.w | ((d & (W - 1)) << 20);
            lpos = atomicAdd(&ptr[b], 1u);
            if (lpos < (unsigned)CAP) slab[b * CAP + lpos] = val;
            else perm[atomicAdd(&fill[b], 1u)] = val;
        }
    } else {
        for (int li = tid; li < total; li += RB) {
            unsigned d = (unsigned)dst[base0 + li];
            unsigned s = (unsigned)src[base0 + li];
            unsigned b = d >> W_SHIFT;
            unsigned val = s | ((d & (W - 1)) << 20);
            unsigned lpos = atomicAdd(&ptr[b], 1u);
            if (lpos < (unsigned)CAP) slab[b * CAP + lpos] = val;
            else perm[atomicAdd(&fill[b], 1u)] = val;
        }
    }
    __syncthreads();
    if (tid < MAXB) {
        unsigned cnt = min(ptr[tid], (unsigned)CAP);
        gbase[tid] = cnt ? atomicAdd(&fill[tid], cnt) : 0u;
        ptr[tid] = cnt;
    }
    __syncthreads();
    for (int s = tid; s < MAXB * CAP; s += RB) {
        int b = s / CAP;
        int i = s - b * CAP;
        if (i < (int)ptr[b]) perm[gbase[b] + i] = slab[s];
    }
}

// degree count (x2-replicated u32 histogram) -> dinv + xs
__global__ __launch_bounds__(AB) void k_dinv(const unsigned* __restrict__ perm,
                                             const unsigned* __restrict__ fill,
                                             const float2* __restrict__ x,
                                             float* __restrict__ dinv,
                                             __half2* __restrict__ xs,
                                             int N, unsigned C) {
    __shared__ unsigned c[2 * W];
    for (int i = threadIdx.x; i < 2 * W; i += AB) c[i] = 0u;
    __syncthreads();
    int b = blockIdx.x;
    unsigned par = threadIdx.x & 1u;
    unsigned s = (unsigned)b * C, e = fill[b];
    unsigned m = e - s, nv8 = m >> 3;
    const uv4* p4 = (const uv4*)(perm + s);
    for (unsigned j = threadIdx.x; j < nv8; j += AB) {
        uv4 qa = __builtin_nontemporal_load(p4 + 2u * j);
        uv4 qb = __builtin_nontemporal_load(p4 + 2u * j + 1u);
        atomicAdd(&c[((qa.x >> 20) << 1) | par], 1u);
        atomicAdd(&c[((qa.y >> 20) << 1) | par], 1u);
        atomicAdd(&c[((qa.z >> 20) << 1) | par], 1u);
        atomicAdd(&c[((qa.w >> 20) << 1) | par], 1u);
        atomicAdd(&c[((qb.x >> 20) << 1) | par], 1u);
        atomicAdd(&c[((qb.y >> 20) << 1) | par], 1u);
        atomicAdd(&c[((qb.z >> 20) << 1) | par], 1u);
        atomicAdd(&c[((qb.w >> 20) << 1) | par], 1u);
    }
    unsigned t = s + (nv8 << 3) + threadIdx.x;
    if (t < e) atomicAdd(&c[((perm[t] >> 20) << 1) | par], 1u);
    __syncthreads();
    int d0 = b << W_SHIFT;
    for (int l = threadIdx.x; l < W; l += AB) {
        int d = d0 + l;
        if (d < N) {
            unsigned cn = c[2 * l] + c[2 * l + 1];
            float dv = 1.0f / sqrtf((float)(cn + 1u));  // +1 self-loop
            dinv[d] = dv;
            float2 xv = x[d];
            xs[d] = __floats2half2_rn(xv.x * dv, xv.y * dv);
        }
    }
}

// layer1: 1x ds_pk_add_f16 per edge (x4-replicated half2 acc) + full MLP
__global__ __launch_bounds__(AB) void k_acc1(const unsigned* __restrict__ perm,
                                             const unsigned* __restrict__ fill,
                                             const __half2* __restrict__ xs,
                                             const float* __restrict__ dinv,
                                             const float* __restrict__ W1,
                                             const float* __restrict__ b1,
                                             const float* __restrict__ W2,
                                             __half2* __restrict__ h2s,
                                             int N, unsigned C) {
    __shared__ __half2 acc[4 * W];            // x4 replicas, 32 KB
    for (int i = threadIdx.x; i < 4 * W; i += AB)
        ((unsigned*)acc)[i] = 0u;
    __syncthreads();
    int b = blockIdx.x;
    unsigned par = threadIdx.x & 3u;
    unsigned s = (unsigned)b * C, e = fill[b];
    unsigned m = e - s, nv8 = m >> 3;
    const uv4* p4 = (const uv4*)(perm + s);
    for (unsigned j = threadIdx.x; j < nv8; j += AB) {
        uv4 qa = __builtin_nontemporal_load(p4 + 2u * j);
        uv4 qb = __builtin_nontemporal_load(p4 + 2u * j + 1u);
        __half2 v0 = xs[qa.x & 0xFFFFFu];
        __half2 v1 = xs[qa.y & 0xFFFFFu];
        __half2 v2 = xs[qa.z & 0xFFFFFu];
        __half2 v3 = xs[qa.w & 0xFFFFFu];
        __half2 v4 = xs[qb.x & 0xFFFFFu];
        __half2 v5 = xs[qb.y & 0xFFFFFu];
        __half2 v6 = xs[qb.z & 0xFFFFFu];
        __half2 v7 = xs[qb.w & 0xFFFFFu];
        unsafeAtomicAdd(&acc[((qa.x >> 20) << 2) | par], v0);
        unsafeAtomicAdd(&acc[((qa.y >> 20) << 2) | par], v1);
        unsafeAtomicAdd(&acc[((qa.z >> 20) << 2) | par], v2);
        unsafeAtomicAdd(&acc[((qa.w >> 20) << 2) | par], v3);
        unsafeAtomicAdd(&acc[((qb.x >> 20) << 2) | par], v4);
        unsafeAtomicAdd(&acc[((qb.y >> 20) << 2) | par], v5);
        unsafeAtomicAdd(&acc[((qb.z >> 20) << 2) | par], v6);
        unsafeAtomicAdd(&acc[((qb.w >> 20) << 2) | par], v7);
    }
    unsigned t = s + (nv8 << 3) + threadIdx.x;
    if (t < e) {
        unsigned p = perm[t];
        unsafeAtomicAdd(&acc[((p >> 20) << 2) | par], xs[p & 0xFFFFFu]);
    }
    __syncthreads();
    int d0 = b << W_SHIFT;
    float w10 = W1[0], w11 = W1[1], w12 = W1[2], w13 = W1[3];
    float w14 = W1[4], w15 = W1[5], w16 = W1[6], w17 = W1[7];
    float bb0 = b1[0], bb1 = b1[1], bb2 = b1[2], bb3 = b1[3];
    float u0 = W2[0], u1 = W2[1], u2 = W2[2], u3 = W2[3];
    float u4 = W2[4], u5 = W2[5], u6 = W2[6], u7 = W2[7];
    for (int l = threadIdx.x; l < W; l += AB) {
        int d = d0 + l;
        if (d < N) {
            float dv = dinv[d];
            float2 r0 = __half22float2(acc[4 * l]);
            float2 r1 = __half22float2(acc[4 * l + 1]);
            float2 r2 = __half22float2(acc[4 * l + 2]);
            float2 r3 = __half22float2(acc[4 * l + 3]);
            float2 self = __half22float2(xs[d]);
            float Sx = (r0.x + r1.x) + (r2.x + r3.x) + self.x;
            float Sy = (r0.y + r1.y) + (r2.y + r3.y) + self.y;
            float a0 = fmaxf(fmaf(Sy, w14, Sx * w10) * dv + bb0, 0.0f);
            float a1 = fmaxf(fmaf(Sy, w15, Sx * w11) * dv + bb1, 0.0f);
            float a2 = fmaxf(fmaf(Sy, w16, Sx * w12) * dv + bb2, 0.0f);
            float a3 = fmaxf(fmaf(Sy, w17, Sx * w13) * dv + bb3, 0.0f);
            float hx = (a0 * u0 + a1 * u2 + a2 * u4 + a3 * u6) * dv;
            float hy = (a0 * u1 + a1 * u3 + a2 * u5 + a3 * u7) * dv;
            h2s[d] = __floats2half2_rn(hx, hy);
        }
    }
}

// layer2: 1x ds_pk_add_f16 per edge + bias epilogue
__global__ __launch_bounds__(AB) void k_acc2(const unsigned* __restrict__ perm,
                                             const unsigned* __restrict__ fill,
                                             const __half2* __restrict__ h2s,
                                             const float* __restrict__ dinv,
                                             const float* __restrict__ b2,
                                             float2* __restrict__ out,
                                             int N, unsigned C) {
    __shared__ __half2 acc[4 * W];            // x4 replicas, 32 KB
    for (int i = threadIdx.x; i < 4 * W; i += AB)
        ((unsigned*)acc)[i] = 0u;
    __syncthreads();
    int b = blockIdx.x;
    unsigned par = threadIdx.x & 3u;
    unsigned s = (unsigned)b * C, e = fill[b];
    unsigned m = e - s, nv8 = m >> 3;
    const uv4* p4 = (const uv4*)(perm + s);
    for (unsigned j = threadIdx.x; j < nv8; j += AB) {
        uv4 qa = __builtin_nontemporal_load(p4 + 2u * j);
        uv4 qb = __builtin_nontemporal_load(p4 + 2u * j + 1u);
        __half2 v0 = h2s[qa.x & 0xFFFFFu];
        __half2 v1 = h2s[qa.y & 0xFFFFFu];
        __half2 v2 = h2s[qa.z & 0xFFFFFu];
        __half2 v3 = h2s[qa.w & 0xFFFFFu];
        __half2 v4 = h2s[qb.x & 0xFFFFFu];
        __half2 v5 = h2s[qb.y & 0xFFFFFu];
        __half2 v6 = h2s[qb.z & 0xFFFFFu];
        __half2 v7 = h2s[qb.w & 0xFFFFFu];
        unsafeAtomicAdd(&acc[((qa.x >> 20) << 2) | par], v0);
        unsafeAtomicAdd(&acc[((qa.y >> 20) << 2) | par], v1);
        unsafeAtomicAdd(&acc[((qa.z >> 20) << 2) | par], v2);
        unsafeAtomicAdd(&acc[((qa.w >> 20) << 2) | par], v3);
        unsafeAtomicAdd(&acc[((qb.x >> 20) << 2) | par], v4);
        unsafeAtomicAdd(&acc[((qb.y >> 20) << 2) | par], v5);
        unsafeAtomicAdd(&acc[((qb.z >> 20) << 2) | par], v6);
        unsafeAtomicAdd(&acc[((qb.w >> 20) << 2) | par], v7);
    }
    unsigned t = s + (nv8 << 3) + threadIdx.x;
    if (t < e) {
        unsigned p = perm[t];
        unsafeAtomicAdd(&acc[((p >> 20) << 2) | par], h2s[p & 0xFFFFFu]);
    }
    __syncthreads();
    int d0 = b << W_SHIFT;
    float bb0 = b2[0], bb1 = b2[1];
    for (int l = threadIdx.x; l < W; l += AB) {
        int d = d0 + l;
        if (d < N) {
            float dv = dinv[d];
            float2 r0 = __half22float2(acc[4 * l]);
            float2 r1 = __half22float2(acc[4 * l + 1]);
            float2 r2 = __half22float2(acc[4 * l + 2]);
            float2 r3 = __half22float2(acc[4 * l + 3]);
            float2 self = __half22float2(h2s[d]);
            float Sx = (r0.x + r1.x) + (r2.x + r3.x) + self.x;
            float Sy = (r0.y + r1.y) + (r2.y + r3.y) + self.y;
            out[d] = make_float2(Sx * dv + bb0, Sy * dv + bb1);
        }
    }
}

// ---------------- fallback (R1-style, only if workspace too small) ----------

__global__ __launch_bounds__(256) void f_init_deg(unsigned* deg, int n) {
    int i = blockIdx.x * 256 + threadIdx.x;
    if (i < n) deg[i] = 1u;
}
__global__ __launch_bounds__(256) void f_count_deg(const int* dst, unsigned* deg, int E) {
    int e = blockIdx.x * 256 + threadIdx.x;
    if (e < E) atomicAdd(&deg[dst[e]], 1u);
}
__global__ __launch_bounds__(256) void f_node1(const float2* x, const float* W1,
                                               const unsigned* deg, float* dinv,
                                               float4* h1s, float4* agg1, int n) {
    int i = blockIdx.x * 256 + threadIdx.x;
    if (i >= n) return;
    float dv = 1.0f / sqrtf((float)deg[i]);
    dinv[i] = dv;
    float2 xv = x[i];
    float4 h;
    h.x = fmaf(xv.y, W1[4], xv.x * W1[0]) * dv;
    h.y = fmaf(xv.y, W1[5], xv.x * W1[1]) * dv;
    h.z = fmaf(xv.y, W1[6], xv.x * W1[2]) * dv;
    h.w = fmaf(xv.y, W1[7], xv.x * W1[3]) * dv;
    h1s[i] = h;
    agg1[i] = make_float4(h.x * dv, h.y * dv, h.z * dv, h.w * dv);
}
__global__ __launch_bounds__(256) void f_edge1(const int* src, const int* dst,
                                               const float* dinv, const float4* h1s,
                                               float* agg1, int E) {
    int e = blockIdx.x * 256 + threadIdx.x;
    if (e >= E) return;
    int s = src[e], d = dst[e];
    float w = dinv[d];
    float4 m = h1s[s];
    float* p = agg1 + 4ll * d;
    unsafeAtomicAdd(p + 0, m.x * w);
    unsafeAtomicAdd(p + 1, m.y * w);
    unsafeAtomicAdd(p + 2, m.z * w);
    unsafeAtomicAdd(p + 3, m.w * w);
}
__global__ __launch_bounds__(256) void f_node2(const float4* agg1, const float* b1,
                                               const float* W2, const float* b2,
                                               const float* dinv, float2* h2s,
                                               float2* out, int n) {
    int i = blockIdx.x * 256 + threadIdx.x;
    if (i >= n) return;
    float4 a = agg1[i];
    a.x = fmaxf(a.x + b1[0], 0.0f);
    a.y = fmaxf(a.y + b1[1], 0.0f);
    a.z = fmaxf(a.z + b1[2], 0.0f);
    a.w = fmaxf(a.w + b1[3], 0.0f);
    float dv = dinv[i];
    float2 h;
    h.x = (a.x * W2[0] + a.y * W2[2] + a.z * W2[4] + a.w * W2[6]) * dv;
    h.y = (a.x * W2[1] + a.y * W2[3] + a.z * W2[5] + a.w * W2[7]) * dv;
    h2s[i] = h;
    out[i] = make_float2(b2[0] + h.x * dv, b2[1] + h.y * dv);
}
__global__ __launch_bounds__(256) void f_edge2(const int* src, const int* dst,
                                               const float* dinv, const float2* h2s,
                                               float* out, int E) {
    int e = blockIdx.x * 256 + threadIdx.x;
    if (e >= E) return;
    int s = src[e], d = dst[e];
    float w = dinv[d];
    float2 m = h2s[s];
    float* p = out + 2ll * d;
    unsafeAtomicAdd(p + 0, m.x * w);
    unsafeAtomicAdd(p + 1, m.y * w);
}

extern "C" void kernel_launch(void* const* d_in, const int* in_sizes, int n_in,
                              void* d_out, int out_size, void* d_ws, size_t ws_size,
                              hipStream_t stream) {
    const float* x  = (const float*)d_in[0];
    const int* ei   = (const int*)d_in[1];
    const float* W1 = (const float*)d_in[2];
    const float* b1 = (const float*)d_in[3];
    const float* W2 = (const float*)d_in[4];
    const float* b2 = (const float*)d_in[5];
    float* out = (float*)d_out;

    const int N = in_sizes[0] / 2;
    const int E = in_sizes[1] / 2;
    const int* src = ei;
    const int* dst = ei + E;
    const int NB = (N + W - 1) >> W_SHIFT;

    char* ws = (char*)d_ws;
    const int gN = (N + 255) / 256;
    const int gE = (E + 255) / 256;

    // slab capacity: mean fill E/NB (~32.7K, sigma~181); margin 4096 (>20σ)
    size_t fixed = 32768 + (size_t)12 * N;   // fill | dinv | xs | h2s
    long avail = (long)ws_size - (long)fixed;
    long Cmax = (avail > 0) ? avail / (4L * NB) : 0;
    long Cmin = (long)(E / (NB > 0 ? NB : 1)) + 4096;
    long Cw = (Cmax > Cmin + 8192) ? (Cmin + 8192) : Cmax;
    unsigned C = (unsigned)(Cw & ~7L);       // multiple of 8 for uint4x2 loads
    bool fast = ((long)C >= Cmin) && (NB <= MAXB) && (N <= (1 << 20));

    if (fast) {
        unsigned* fill = (unsigned*)(ws);                          // NB entries
        float*    dinv = (float*)(ws + 32768);
        __half2*  xs   = (__half2*)(ws + 32768 + (size_t)4 * N);
        __half2*  h2s  = (__half2*)(ws + 32768 + (size_t)8 * N);
        unsigned* perm = (unsigned*)(ws + fixed);

        k_zero_fill<<<(NB + 255) / 256, 256, 0, stream>>>(fill, NB, C);
        k_reorder<<<(E + CHUNK - 1) / CHUNK, RB, 0, stream>>>(src, dst, fill, perm, E);
        k_dinv<<<NB, AB, 0, stream>>>(perm, fill, (const float2*)x, dinv, xs, N, C);
        k_acc1<<<NB, AB, 0, stream>>>(perm, fill, xs, dinv, W1, b1, W2, h2s, N, C);
        k_acc2<<<NB, AB, 0, stream>>>(perm, fill, h2s, dinv, b2, (float2*)out, N, C);
    } else {
        unsigned* deg = (unsigned*)(ws);
        float* dinv   = (float*)(ws + (size_t)4 * N);
        float* h1s    = (float*)(ws + (size_t)8 * N);
        float* agg1   = (float*)(ws + (size_t)24 * N);
        float* h2s    = h1s;

        f_init_deg<<<gN, 256, 0, stream>>>(deg, N);
        f_count_deg<<<gE, 256, 0, stream>>>(dst, deg, E);
        f_node1<<<gN, 256, 0, stream>>>((const float2*)x, W1, deg, dinv,
                                        (float4*)h1s, (float4*)agg1, N);
        f_edge1<<<gE, 256, 0, stream>>>(src, dst, dinv, (const float4*)h1s, agg1, E);
        f_node2<<<gN, 256, 0, stream>>>((const float4*)agg1, b1, W2, b2, dinv,
                                        (float2*)h2s, (float2*)out, N);
        f_edge2<<<gE, 256, 0, stream>>>(src, dst, dinv, (const float2*)h2s, out, E);
    }
}

// Round 8
// 434.196 us; speedup vs baseline: 2.3006x; 1.0040x over previous
//
#include <hip/hip_runtime.h>
#include <hip/hip_fp16.h>

// GCN 2-layer forward, MI355X. R19: remove zero_fill dispatch (cnt-based
// slab pointers + hipMemsetAsync), nt loads for reorder streams.
// R18 post-mortem: acc pass time invariant to atomic width, conflicts,
// VALU, ILP, AND wave concurrency (occ 35->68%, 97us flat). Model: per-CU
// fixed L1-MSHR / L2 random-request bound ~3.5cyc/edge for 16M random 4B
// gathers in a 4MB table. All 4 passes (reorder/count/acc1/acc2) at
// measured floors; acc passes algorithmically required (2 sparse layers,
// ReLU between), count required (per-src norm before gathers), reorder
// required (LDS-local scatter). Remaining slack = launch structure only.
// Pre-commit: if wall >= 428, declare roofline next round.
// Pipeline: memset(cnt), reorder(slab), dinv(+xs), acc1(pk,+MLP), acc2(pk).

constexpr int W_SHIFT = 11;
constexpr int W = 2048;            // nodes per dst window
constexpr int MAXB = 512;          // max buckets/windows
constexpr int RB = 1024;           // reorder block threads
constexpr int CHUNK = 8192;        // edges per reorder block
constexpr int CAP = 28;            // reorder slab capacity per bucket
constexpr int AB = 1024;           // accumulate block threads

typedef unsigned uv4 __attribute__((ext_vector_type(4)));
typedef int      iv4 __attribute__((ext_vector_type(4)));

// Slab multisplit: single u32 LDS atomic per edge. cnt[b] = edges placed in
// window b so far (absolute slab position = b*C + cnt).
__global__ __launch_bounds__(RB) void k_reorder(const int* __restrict__ src,
                                                const int* __restrict__ dst,
                                                unsigned* __restrict__ cnt,
                                                unsigned* __restrict__ perm,
                                                int E, unsigned C) {
    __shared__ unsigned slab[MAXB * CAP];  // 57344 B
    __shared__ unsigned ptr[MAXB];
    __shared__ unsigned gbase[MAXB];
    int tid = threadIdx.x;
    if (tid < MAXB) ptr[tid] = 0u;
    __syncthreads();
    long base0 = (long)blockIdx.x * CHUNK;
    int total = (int)min((long)CHUNK, (long)E - base0);
    bool full = (total == CHUNK);

    if (full) {
        const iv4* dv4 = (const iv4*)(dst + base0);
        const iv4* sv4 = (const iv4*)(src + base0);
        #pragma unroll
        for (int k = 0; k < 2; k++) {
            iv4 dq = __builtin_nontemporal_load(dv4 + k * RB + tid);
            iv4 sq = __builtin_nontemporal_load(sv4 + k * RB + tid);
            unsigned d, b, val, lpos;
            d = (unsigned)dq.x; b = d >> W_SHIFT;
            val = (unsigned)sq.x | ((d & (W - 1)) << 20);
            lpos = atomicAdd(&ptr[b], 1u);
            if (lpos < (unsigned)CAP) slab[b * CAP + lpos] = val;
            else perm[b * C + atomicAdd(&cnt[b], 1u)] = val;
            d = (unsigned)dq.y; b = d >> W_SHIFT;
            val = (unsigned)sq.y | ((d & (W - 1)) << 20);
            lpos = atomicAdd(&ptr[b], 1u);
            if (lpos < (unsigned)CAP) slab[b * CAP + lpos] = val;
            else perm[b * C + atomicAdd(&cnt[b], 1u)] = val;
            d = (unsigned)dq.z; b = d >> W_SHIFT;
            val = (unsigned)sq.z | ((d & (W - 1)) << 20);
            lpos = atomicAdd(&ptr[b], 1u);
            if (lpos < (unsigned)CAP) slab[b * CAP + lpos] = val;
            else perm[b * C + atomicAdd(&cnt[b], 1u)] = val;
            d = (unsigned)dq.w; b = d >> W_SHIFT;
            val = (unsigned)sq.w | ((d & (W - 1)) << 20);
            lpos = atomicAdd(&ptr[b], 1u);
            if (lpos < (unsigned)CAP) slab[b * CAP + lpos] = val;
            else perm[b * C + atomicAdd(&cnt[b], 1u)] = val;
        }
    } else {
        for (int li = tid; li < total; li += RB) {
            unsigned d = (unsigned)dst[base0 + li];
            unsigned s = (unsigned)src[base0 + li];
            unsigned b = d >> W_SHIFT;
            unsigned val = s | ((d & (W - 1)) << 20);
            unsigned lpos = atomicAdd(&ptr[b], 1u);
            if (lpos < (unsigned)CAP) slab[b * CAP + lpos] = val;
            else perm[b * C + atomicAdd(&cnt[b], 1u)] = val;
        }
    }
    __syncthreads();
    if (tid < MAXB) {
        unsigned c = min(ptr[tid], (unsigned)CAP);
        gbase[tid] = c ? ((unsigned)tid * C + atomicAdd(&cnt[tid], c)) : 0u;
        ptr[tid] = c;
    }
    __syncthreads();
    for (int s = tid; s < MAXB * CAP; s += RB) {
        int b = s / CAP;
        int i = s - b * CAP;
        if (i < (int)ptr[b]) perm[gbase[b] + i] = slab[s];
    }
}

// degree count (x2-replicated u32 histogram) -> dinv + xs
__global__ __launch_bounds__(AB) void k_dinv(const unsigned* __restrict__ perm,
                                             const unsigned* __restrict__ cnt,
                                             const float2* __restrict__ x,
                                             float* __restrict__ dinv,
                                             __half2* __restrict__ xs,
                                             int N, unsigned C) {
    __shared__ unsigned c[2 * W];
    for (int i = threadIdx.x; i < 2 * W; i += AB) c[i] = 0u;
    __syncthreads();
    int b = blockIdx.x;
    unsigned par = threadIdx.x & 1u;
    unsigned s = (unsigned)b * C, e = s + cnt[b];
    unsigned m = e - s, nv8 = m >> 3;
    const uv4* p4 = (const uv4*)(perm + s);
    for (unsigned j = threadIdx.x; j < nv8; j += AB) {
        uv4 qa = __builtin_nontemporal_load(p4 + 2u * j);
        uv4 qb = __builtin_nontemporal_load(p4 + 2u * j + 1u);
        atomicAdd(&c[((qa.x >> 20) << 1) | par], 1u);
        atomicAdd(&c[((qa.y >> 20) << 1) | par], 1u);
        atomicAdd(&c[((qa.z >> 20) << 1) | par], 1u);
        atomicAdd(&c[((qa.w >> 20) << 1) | par], 1u);
        atomicAdd(&c[((qb.x >> 20) << 1) | par], 1u);
        atomicAdd(&c[((qb.y >> 20) << 1) | par], 1u);
        atomicAdd(&c[((qb.z >> 20) << 1) | par], 1u);
        atomicAdd(&c[((qb.w >> 20) << 1) | par], 1u);
    }
    unsigned t = s + (nv8 << 3) + threadIdx.x;
    if (t < e) atomicAdd(&c[((perm[t] >> 20) << 1) | par], 1u);
    __syncthreads();
    int d0 = b << W_SHIFT;
    for (int l = threadIdx.x; l < W; l += AB) {
        int d = d0 + l;
        if (d < N) {
            unsigned cn = c[2 * l] + c[2 * l + 1];
            float dv = 1.0f / sqrtf((float)(cn + 1u));  // +1 self-loop
            dinv[d] = dv;
            float2 xv = x[d];
            xs[d] = __floats2half2_rn(xv.x * dv, xv.y * dv);
        }
    }
}

// layer1: 1x ds_pk_add_f16 per edge (x4-replicated half2 acc) + full MLP
__global__ __launch_bounds__(AB) void k_acc1(const unsigned* __restrict__ perm,
                                             const unsigned* __restrict__ cnt,
                                             const __half2* __restrict__ xs,
                                             const float* __restrict__ dinv,
                                             const float* __restrict__ W1,
                                             const float* __restrict__ b1,
                                             const float* __restrict__ W2,
                                             __half2* __restrict__ h2s,
                                             int N, unsigned C) {
    __shared__ __half2 acc[4 * W];            // x4 replicas, 32 KB
    for (int i = threadIdx.x; i < 4 * W; i += AB)
        ((unsigned*)acc)[i] = 0u;
    __syncthreads();
    int b = blockIdx.x;
    unsigned par = threadIdx.x & 3u;
    unsigned s = (unsigned)b * C, e = s + cnt[b];
    unsigned m = e - s, nv8 = m >> 3;
    const uv4* p4 = (const uv4*)(perm + s);
    for (unsigned j = threadIdx.x; j < nv8; j += AB) {
        uv4 qa = __builtin_nontemporal_load(p4 + 2u * j);
        uv4 qb = __builtin_nontemporal_load(p4 + 2u * j + 1u);
        __half2 v0 = xs[qa.x & 0xFFFFFu];
        __half2 v1 = xs[qa.y & 0xFFFFFu];
        __half2 v2 = xs[qa.z & 0xFFFFFu];
        __half2 v3 = xs[qa.w & 0xFFFFFu];
        __half2 v4 = xs[qb.x & 0xFFFFFu];
        __half2 v5 = xs[qb.y & 0xFFFFFu];
        __half2 v6 = xs[qb.z & 0xFFFFFu];
        __half2 v7 = xs[qb.w & 0xFFFFFu];
        unsafeAtomicAdd(&acc[((qa.x >> 20) << 2) | par], v0);
        unsafeAtomicAdd(&acc[((qa.y >> 20) << 2) | par], v1);
        unsafeAtomicAdd(&acc[((qa.z >> 20) << 2) | par], v2);
        unsafeAtomicAdd(&acc[((qa.w >> 20) << 2) | par], v3);
        unsafeAtomicAdd(&acc[((qb.x >> 20) << 2) | par], v4);
        unsafeAtomicAdd(&acc[((qb.y >> 20) << 2) | par], v5);
        unsafeAtomicAdd(&acc[((qb.z >> 20) << 2) | par], v6);
        unsafeAtomicAdd(&acc[((qb.w >> 20) << 2) | par], v7);
    }
    unsigned t = s + (nv8 << 3) + threadIdx.x;
    if (t < e) {
        unsigned p = perm[t];
        unsafeAtomicAdd(&acc[((p >> 20) << 2) | par], xs[p & 0xFFFFFu]);
    }
    __syncthreads();
    int d0 = b << W_SHIFT;
    float w10 = W1[0], w11 = W1[1], w12 = W1[2], w13 = W1[3];
    float w14 = W1[4], w15 = W1[5], w16 = W1[6], w17 = W1[7];
    float bb0 = b1[0], bb1 = b1[1], bb2 = b1[2], bb3 = b1[3];
    float u0 = W2[0], u1 = W2[1], u2 = W2[2], u3 = W2[3];
    float u4 = W2[4], u5 = W2[5], u6 = W2[6], u7 = W2[7];
    for (int l = threadIdx.x; l < W; l += AB) {
        int d = d0 + l;
        if (d < N) {
            float dv = dinv[d];
            float2 r0 = __half22float2(acc[4 * l]);
            float2 r1 = __half22float2(acc[4 * l + 1]);
            float2 r2 = __half22float2(acc[4 * l + 2]);
            float2 r3 = __half22float2(acc[4 * l + 3]);
            float2 self = __half22float2(xs[d]);
            float Sx = (r0.x + r1.x) + (r2.x + r3.x) + self.x;
            float Sy = (r0.y + r1.y) + (r2.y + r3.y) + self.y;
            float a0 = fmaxf(fmaf(Sy, w14, Sx * w10) * dv + bb0, 0.0f);
            float a1 = fmaxf(fmaf(Sy, w15, Sx * w11) * dv + bb1, 0.0f);
            float a2 = fmaxf(fmaf(Sy, w16, Sx * w12) * dv + bb2, 0.0f);
            float a3 = fmaxf(fmaf(Sy, w17, Sx * w13) * dv + bb3, 0.0f);
            float hx = (a0 * u0 + a1 * u2 + a2 * u4 + a3 * u6) * dv;
            float hy = (a0 * u1 + a1 * u3 + a2 * u5 + a3 * u7) * dv;
            h2s[d] = __floats2half2_rn(hx, hy);
        }
    }
}

// layer2: 1x ds_pk_add_f16 per edge + bias epilogue
__global__ __launch_bounds__(AB) void k_acc2(const unsigned* __restrict__ perm,
                                             const unsigned* __restrict__ cnt,
                                             const __half2* __restrict__ h2s,
                                             const float* __restrict__ dinv,
                                             const float* __restrict__ b2,
                                             float2* __restrict__ out,
                                             int N, unsigned C) {
    __shared__ __half2 acc[4 * W];            // x4 replicas, 32 KB
    for (int i = threadIdx.x; i < 4 * W; i += AB)
        ((unsigned*)acc)[i] = 0u;
    __syncthreads();
    int b = blockIdx.x;
    unsigned par = threadIdx.x & 3u;
    unsigned s = (unsigned)b * C, e = s + cnt[b];
    unsigned m = e - s, nv8 = m >> 3;
    const uv4* p4 = (const uv4*)(perm + s);
    for (unsigned j = threadIdx.x; j < nv8; j += AB) {
        uv4 qa = __builtin_nontemporal_load(p4 + 2u * j);
        uv4 qb = __builtin_nontemporal_load(p4 + 2u * j + 1u);
        __half2 v0 = h2s[qa.x & 0xFFFFFu];
        __half2 v1 = h2s[qa.y & 0xFFFFFu];
        __half2 v2 = h2s[qa.z & 0xFFFFFu];
        __half2 v3 = h2s[qa.w & 0xFFFFFu];
        __half2 v4 = h2s[qb.x & 0xFFFFFu];
        __half2 v5 = h2s[qb.y & 0xFFFFFu];
        __half2 v6 = h2s[qb.z & 0xFFFFFu];
        __half2 v7 = h2s[qb.w & 0xFFFFFu];
        unsafeAtomicAdd(&acc[((qa.x >> 20) << 2) | par], v0);
        unsafeAtomicAdd(&acc[((qa.y >> 20) << 2) | par], v1);
        unsafeAtomicAdd(&acc[((qa.z >> 20) << 2) | par], v2);
        unsafeAtomicAdd(&acc[((qa.w >> 20) << 2) | par], v3);
        unsafeAtomicAdd(&acc[((qb.x >> 20) << 2) | par], v4);
        unsafeAtomicAdd(&acc[((qb.y >> 20) << 2) | par], v5);
        unsafeAtomicAdd(&acc[((qb.z >> 20) << 2) | par], v6);
        unsafeAtomicAdd(&acc[((qb.w >> 20) << 2) | par], v7);
    }
    unsigned t = s + (nv8 << 3) + threadIdx.x;
    if (t < e) {
        unsigned p = perm[t];
        unsafeAtomicAdd(&acc[((p >> 20) << 2) | par], h2s[p & 0xFFFFFu]);
    }
    __syncthreads();
    int d0 = b << W_SHIFT;
    float bb0 = b2[0], bb1 = b2[1];
    for (int l = threadIdx.x; l < W; l += AB) {
        int d = d0 + l;
        if (d < N) {
            float dv = dinv[d];
            float2 r0 = __half22float2(acc[4 * l]);
            float2 r1 = __half22float2(acc[4 * l + 1]);
            float2 r2 = __half22float2(acc[4 * l + 2]);
            float2 r3 = __half22float2(acc[4 * l + 3]);
            float2 self = __half22float2(h2s[d]);
            float Sx = (r0.x + r1.x) + (r2.x + r3.x) + self.x;
            float Sy = (r0.y + r1.y) + (r2.y + r3.y) + self.y;
            out[d] = make_float2(Sx * dv + bb0, Sy * dv + bb1);
        }
    }
}

// ---------------- fallback (R1-style, only if workspace too small) ----------

__global__ __launch_bounds__(256) void f_init_deg(unsigned* deg, int n) {
    int i = blockIdx.x * 256 + threadIdx.x;
    if (i < n) deg[i] = 1u;
}
__global__ __launch_bounds__(256) void f_count_deg(const int* dst, unsigned* deg, int E) {
    int e = blockIdx.x * 256 + threadIdx.x;
    if (e < E) atomicAdd(&deg[dst[e]], 1u);
}
__global__ __launch_bounds__(256) void f_node1(const float2* x, const float* W1,
                                               const unsigned* deg, float* dinv,
                                               float4* h1s, float4* agg1, int n) {
    int i = blockIdx.x * 256 + threadIdx.x;
    if (i >= n) return;
    float dv = 1.0f / sqrtf((float)deg[i]);
    dinv[i] = dv;
    float2 xv = x[i];
    float4 h;
    h.x = fmaf(xv.y, W1[4], xv.x * W1[0]) * dv;
    h.y = fmaf(xv.y, W1[5], xv.x * W1[1]) * dv;
    h.z = fmaf(xv.y, W1[6], xv.x * W1[2]) * dv;
    h.w = fmaf(xv.y, W1[7], xv.x * W1[3]) * dv;
    h1s[i] = h;
    agg1[i] = make_float4(h.x * dv, h.y * dv, h.z * dv, h.w * dv);
}
__global__ __launch_bounds__(256) void f_edge1(const int* src, const int* dst,
                                               const float* dinv, const float4* h1s,
                                               float* agg1, int E) {
    int e = blockIdx.x * 256 + threadIdx.x;
    if (e >= E) return;
    int s = src[e], d = dst[e];
    float w = dinv[d];
    float4 m = h1s[s];
    float* p = agg1 + 4ll * d;
    unsafeAtomicAdd(p + 0, m.x * w);
    unsafeAtomicAdd(p + 1, m.y * w);
    unsafeAtomicAdd(p + 2, m.z * w);
    unsafeAtomicAdd(p + 3, m.w * w);
}
__global__ __launch_bounds__(256) void f_node2(const float4* agg1, const float* b1,
                                               const float* W2, const float* b2,
                                               const float* dinv, float2* h2s,
                                               float2* out, int n) {
    int i = blockIdx.x * 256 + threadIdx.x;
    if (i >= n) return;
    float4 a = agg1[i];
    a.x = fmaxf(a.x + b1[0], 0.0f);
    a.y = fmaxf(a.y + b1[1], 0.0f);
    a.z = fmaxf(a.z + b1[2], 0.0f);
    a.w = fmaxf(a.w + b1[3], 0.0f);
    float dv = dinv[i];
    float2 h;
    h.x = (a.x * W2[0] + a.y * W2[2] + a.z * W2[4] + a.w * W2[6]) * dv;
    h.y = (a.x * W2[1] + a.y * W2[3] + a.z * W2[5] + a.w * W2[7]) * dv;
    h2s[i] = h;
    out[i] = make_float2(b2[0] + h.x * dv, b2[1] + h.y * dv);
}
__global__ __launch_bounds__(256) void f_edge2(const int* src, const int* dst,
                                               const float* dinv, const float2* h2s,
                                               float* out, int E) {
    int e = blockIdx.x * 256 + threadIdx.x;
    if (e >= E) return;
    int s = src[e], d = dst[e];
    float w = dinv[d];
    float2 m = h2s[s];
    float* p = out + 2ll * d;
    unsafeAtomicAdd(p + 0, m.x * w);
    unsafeAtomicAdd(p + 1, m.y * w);
}

extern "C" void kernel_launch(void* const* d_in, const int* in_sizes, int n_in,
                              void* d_out, int out_size, void* d_ws, size_t ws_size,
                              hipStream_t stream) {
    const float* x  = (const float*)d_in[0];
    const int* ei   = (const int*)d_in[1];
    const float* W1 = (const float*)d_in[2];
    const float* b1 = (const float*)d_in[3];
    const float* W2 = (const float*)d_in[4];
    const float* b2 = (const float*)d_in[5];
    float* out = (float*)d_out;

    const int N = in_sizes[0] / 2;
    const int E = in_sizes[1] / 2;
    const int* src = ei;
    const int* dst = ei + E;
    const int NB = (N + W - 1) >> W_SHIFT;

    char* ws = (char*)d_ws;
    const int gN = (N + 255) / 256;
    const int gE = (E + 255) / 256;

    // slab capacity: mean fill E/NB (~32.7K, sigma~181); margin 4096 (>20σ)
    size_t fixed = 32768 + (size_t)12 * N;   // cnt | dinv | xs | h2s
    long avail = (long)ws_size - (long)fixed;
    long Cmax = (avail > 0) ? avail / (4L * NB) : 0;
    long Cmin = (long)(E / (NB > 0 ? NB : 1)) + 4096;
    long Cw = (Cmax > Cmin + 8192) ? (Cmin + 8192) : Cmax;
    unsigned C = (unsigned)(Cw & ~7L);       // multiple of 8 for uint4x2 loads
    bool fast = ((long)C >= Cmin) && (NB <= MAXB) && (N <= (1 << 20));

    if (fast) {
        unsigned* cnt  = (unsigned*)(ws);                          // NB entries
        float*    dinv = (float*)(ws + 32768);
        __half2*  xs   = (__half2*)(ws + 32768 + (size_t)4 * N);
        __half2*  h2s  = (__half2*)(ws + 32768 + (size_t)8 * N);
        unsigned* perm = (unsigned*)(ws + fixed);

        hipMemsetAsync(cnt, 0, (size_t)NB * 4, stream);
        k_reorder<<<(E + CHUNK - 1) / CHUNK, RB, 0, stream>>>(src, dst, cnt, perm, E, C);
        k_dinv<<<NB, AB, 0, stream>>>(perm, cnt, (const float2*)x, dinv, xs, N, C);
        k_acc1<<<NB, AB, 0, stream>>>(perm, cnt, xs, dinv, W1, b1, W2, h2s, N, C);
        k_acc2<<<NB, AB, 0, stream>>>(perm, cnt, h2s, dinv, b2, (float2*)out, N, C);
    } else {
        unsigned* deg = (unsigned*)(ws);
        float* dinv   = (float*)(ws + (size_t)4 * N);
        float* h1s    = (float*)(ws + (size_t)8 * N);
        float* agg1   = (float*)(ws + (size_t)24 * N);
        float* h2s    = h1s;

        f_init_deg<<<gN, 256, 0, stream>>>(deg, N);
        f_count_deg<<<gE, 256, 0, stream>>>(dst, deg, E);
        f_node1<<<gN, 256, 0, stream>>>((const float2*)x, W1, deg, dinv,
                                        (float4*)h1s, (float4*)agg1, N);
        f_edge1<<<gE, 256, 0, stream>>>(src, dst, dinv, (const float4*)h1s, agg1, E);
        f_node2<<<gN, 256, 0, stream>>>((const float4*)agg1, b1, W2, b2, dinv,
                                        (float2*)h2s, (float2*)out, N);
        f_edge2<<<gE, 256, 0, stream>>>(src, dst, dinv, (const float2*)h2s, out, E);
    }
}